// Round 1
// baseline (6965.573 us; speedup 1.0000x reference)
//
#include <hip/hip_runtime.h>

// ---------------------------------------------------------------------------
// GraphConv_8847632629923 : full fp32 pipeline
//   dense per-graph adjacency -> batched GEMM GCN -> SAGPool (rank-select)
//   -> MHA with v-GEMM algebraically eliminated -> readout
// Workspace requirement: ~226 MB (floats):
//   dinv[N] | A_raw[B,200,200] | buf0[N,128] | buf1[N,128] | z[N,128]
//   | xc[N,512] | pooled[B,512]
// ---------------------------------------------------------------------------

#define GB   256          // batch (graphs)
#define SS   200          // nodes per graph
#define KIN  200          // input features
#define HD   128          // hidden
#define NLAY 4
#define NHD  8
#define TOPK 100
#define NT   (GB * SS)    // 51200 nodes
#define EPG_ 6400
#define NE_  (GB * EPG_)  // 1,638,400 edges
#define EMB_ 512

// ---------------- adjacency build ----------------
__global__ __launch_bounds__(256) void k_build_A(const int* __restrict__ src,
                                                 const int* __restrict__ dst,
                                                 float* __restrict__ A) {
  int e = blockIdx.x * 256 + threadIdx.x;
  if (e >= NE_) return;
  int d = dst[e], s = src[e];
  int b = d / SS;
  int dl = d - b * SS;
  int sl = s - b * SS;
  atomicAdd(&A[((size_t)b * SS + dl) * SS + sl], 1.0f);
}

// ---------------- dinv = rsqrt(in_deg + 1) ----------------
__global__ __launch_bounds__(256) void k_dinv(const float* __restrict__ A,
                                              float* __restrict__ dinv) {
  int node = blockIdx.x * 4 + (threadIdx.x >> 6);
  int lane = threadIdx.x & 63;
  const float* r = A + (size_t)node * SS;
  float v = r[lane] + r[lane + 64] + r[lane + 128];
  if (lane < 8) v += r[lane + 192];
#pragma unroll
  for (int o = 32; o; o >>= 1) v += __shfl_xor(v, o);
  if (lane == 0) dinv[node] = rsqrtf(v + 1.0f);
}

// ---------------- node GEMM: out[N,128] = act([in1|in2] @ W + bias) --------
__global__ __launch_bounds__(256) void k_gemm_node(
    const float* __restrict__ in1, int k1,
    const float* __restrict__ in2, int k2,        // optional, stride 128
    const float* __restrict__ W,                  // [k1+k2][128]
    const float* __restrict__ bias,               // [128] or null
    float* __restrict__ out, int doTanh) {
  const int row0 = (blockIdx.x >> 1) * 64;
  const int n0   = (blockIdx.x & 1) * 64;
  const int t  = threadIdx.x;
  const int tx = t & 15, ty = t >> 4;
  const int K = k1 + k2;
  __shared__ float As[32][68];
  __shared__ float Bs[32][68];
  float acc[4][4] = {{0.f, 0.f, 0.f, 0.f}, {0.f, 0.f, 0.f, 0.f},
                     {0.f, 0.f, 0.f, 0.f}, {0.f, 0.f, 0.f, 0.f}};
  for (int k0 = 0; k0 < K; k0 += 32) {
    __syncthreads();
#pragma unroll
    for (int p = 0; p < 8; ++p) {
      int li = t + p * 256;
      int kk = li & 31, m = li >> 5;
      int kg = k0 + kk;
      int row = row0 + m;
      float v = 0.f;
      if (kg < k1)     v = in1[(size_t)row * k1 + kg];
      else if (kg < K) v = in2[(size_t)row * HD + (kg - k1)];
      As[kk][m] = v;
      int n = li & 63, kb = li >> 6;
      int kg2 = k0 + kb;
      Bs[kb][n] = (kg2 < K) ? W[(size_t)kg2 * HD + n0 + n] : 0.f;
    }
    __syncthreads();
#pragma unroll
    for (int kk = 0; kk < 32; ++kk) {
      float4 av = *reinterpret_cast<const float4*>(&As[kk][ty * 4]);
      float4 wv = *reinterpret_cast<const float4*>(&Bs[kk][tx * 4]);
      float a[4] = {av.x, av.y, av.z, av.w};
      float w[4] = {wv.x, wv.y, wv.z, wv.w};
#pragma unroll
      for (int i = 0; i < 4; ++i)
#pragma unroll
        for (int j = 0; j < 4; ++j) acc[i][j] += a[i] * w[j];
    }
  }
#pragma unroll
  for (int i = 0; i < 4; ++i) {
    int row = row0 + ty * 4 + i;
    int c = n0 + tx * 4;
    float4 r;
    r.x = acc[i][0] + (bias ? bias[c + 0] : 0.f);
    r.y = acc[i][1] + (bias ? bias[c + 1] : 0.f);
    r.z = acc[i][2] + (bias ? bias[c + 2] : 0.f);
    r.w = acc[i][3] + (bias ? bias[c + 3] : 0.f);
    if (doTanh) { r.x = tanhf(r.x); r.y = tanhf(r.y); r.z = tanhf(r.z); r.w = tanhf(r.w); }
    *reinterpret_cast<float4*>(&out[(size_t)row * HD + c]) = r;
  }
}

// --------- GCN aggregation: x1 = tanh( Â @ xw + b ), Â normalized on load ---
__global__ __launch_bounds__(256) void k_gemm_agg(
    const float* __restrict__ A, const float* __restrict__ dinv,
    const float* __restrict__ xw, const float* __restrict__ bias,
    float* __restrict__ out) {
  const int b    = blockIdx.x >> 3;
  const int row0 = ((blockIdx.x >> 1) & 3) * 64;
  const int n0   = (blockIdx.x & 1) * 64;
  const int t  = threadIdx.x;
  const int tx = t & 15, ty = t >> 4;
  const float* Ab = A + (size_t)b * SS * SS;
  const float* dv = dinv + b * SS;
  __shared__ float As[32][68];
  __shared__ float Bs[32][68];
  float acc[4][4] = {{0.f, 0.f, 0.f, 0.f}, {0.f, 0.f, 0.f, 0.f},
                     {0.f, 0.f, 0.f, 0.f}, {0.f, 0.f, 0.f, 0.f}};
  for (int k0 = 0; k0 < SS; k0 += 32) {
    __syncthreads();
#pragma unroll
    for (int p = 0; p < 8; ++p) {
      int li = t + p * 256;
      int kk = li & 31, m = li >> 5;
      int d = row0 + m;
      int sg = k0 + kk;
      float v = 0.f;
      if (d < SS && sg < SS) {
        v = Ab[(size_t)d * SS + sg];
        if (d == sg) v += 1.0f;               // self-loop
        v *= dv[d] * dv[sg];                  // D^-1/2 (A+I) D^-1/2
      }
      As[kk][m] = v;
      int n = li & 63, kb = li >> 6;
      int sg2 = k0 + kb;
      Bs[kb][n] = (sg2 < SS) ? xw[((size_t)b * SS + sg2) * HD + n0 + n] : 0.f;
    }
    __syncthreads();
#pragma unroll
    for (int kk = 0; kk < 32; ++kk) {
      float4 av = *reinterpret_cast<const float4*>(&As[kk][ty * 4]);
      float4 wv = *reinterpret_cast<const float4*>(&Bs[kk][tx * 4]);
      float a[4] = {av.x, av.y, av.z, av.w};
      float w[4] = {wv.x, wv.y, wv.z, wv.w};
#pragma unroll
      for (int i = 0; i < 4; ++i)
#pragma unroll
        for (int j = 0; j < 4; ++j) acc[i][j] += a[i] * w[j];
    }
  }
#pragma unroll
  for (int i = 0; i < 4; ++i) {
    int row = row0 + ty * 4 + i;
    if (row >= SS) continue;
    int c = n0 + tx * 4;
    float4 r;
    r.x = tanhf(acc[i][0] + bias[c + 0]);
    r.y = tanhf(acc[i][1] + bias[c + 1]);
    r.z = tanhf(acc[i][2] + bias[c + 2]);
    r.w = tanhf(acc[i][3] + bias[c + 3]);
    *reinterpret_cast<float4*>(&out[((size_t)b * SS + row) * HD + c]) = r;
  }
}

// ---------------- SAGPool: score, top-k select, padded write ----------------
__global__ __launch_bounds__(256) void k_sag(
    const float* __restrict__ z, const float* __restrict__ A,
    const float* __restrict__ w1, const float* __restrict__ w2,
    const float* __restrict__ sb, float* __restrict__ xc, int layer) {
  const int b = blockIdx.x, t = threadIdx.x;
  __shared__ float w1s[HD], w2s[HD];
  __shared__ float zw1[SS], sc[SS], fac[SS];
  if (t < HD) { w1s[t] = w1[t]; w2s[t] = w2[t]; }
  __syncthreads();
  float a2 = 0.f;
  if (t < SS) {
    const float4* zr = reinterpret_cast<const float4*>(&z[((size_t)b * SS + t) * HD]);
    float a1 = 0.f;
#pragma unroll
    for (int q = 0; q < HD / 4; ++q) {
      float4 v = zr[q];
      a1 += v.x * w1s[4 * q] + v.y * w1s[4 * q + 1] + v.z * w1s[4 * q + 2] + v.w * w1s[4 * q + 3];
      a2 += v.x * w2s[4 * q] + v.y * w2s[4 * q + 1] + v.z * w2s[4 * q + 2] + v.w * w2s[4 * q + 3];
    }
    zw1[t] = a1;
  }
  __syncthreads();
  if (t < SS) {
    // score = A_raw @ (z@w1) + z@w2 + b   (GraphConv aggr='add')
    float s = sb[0] + a2;
    const float4* ar = reinterpret_cast<const float4*>(&A[((size_t)b * SS + t) * SS]);
#pragma unroll 5
    for (int q = 0; q < SS / 4; ++q) {
      float4 v = ar[q];
      s += v.x * zw1[4 * q] + v.y * zw1[4 * q + 1] + v.z * zw1[4 * q + 2] + v.w * zw1[4 * q + 3];
    }
    sc[t] = s;
  }
  __syncthreads();
  if (t < SS) {
    // rank with jax.lax.top_k tie-breaking (first index wins)
    float si = sc[t];
    int cnt = 0;
    for (int j = 0; j < SS; ++j) {
      float sj = sc[j];
      cnt += (sj > si || (sj == si && j < t)) ? 1 : 0;
    }
    fac[t] = (cnt < TOPK) ? tanhf(si) : 0.f;
  }
  __syncthreads();
  for (int idx = t; idx < SS * HD; idx += 256) {
    int row = idx >> 7, c = idx & 127;
    xc[((size_t)b * SS + row) * EMB_ + layer * HD + c] =
        fac[row] * z[((size_t)b * SS + row) * HD + c];
  }
}

// ---------------- MHA: q/k GEMM, scores, softmax, attn-mean, pooled ---------
__global__ __launch_bounds__(256) void k_mha(
    const float* __restrict__ xc, const float* __restrict__ Win,
    const float* __restrict__ bin, float* __restrict__ Sg,
    float* __restrict__ attn, float* __restrict__ pooled) {
  const int b = blockIdx.x, t = threadIdx.x;
  const int tx = t & 15, ty = t >> 4;
  const float* xcb = xc + (size_t)b * SS * EMB_;
  float* Sb = Sg + (size_t)b * SS * SS;      // per-graph score scratch (A_raw reuse)
  float* Ab = attn + (size_t)b * SS * SS;    // attn-mean output (pre-zeroed)
  __shared__ float qT[64][208];              // [d][row], padded
  __shared__ float kT[64][208];
  __shared__ float xcs[32][68];
  __shared__ float Ws[32][68];
  __shared__ float mrow[SS], rl[SS], cp[SS];
  __shared__ float tvec[EMB_];

  for (int h = 0; h < NHD; ++h) {
    // ---- phase A: q (tgt 0) and k (tgt 1), [200,64] each
    for (int tgt = 0; tgt < 2; ++tgt) {
      const int roff = tgt * EMB_ + h * 64;
      for (int m0 = 0; m0 < SS; m0 += 64) {
        float acc[4][4] = {{0.f, 0.f, 0.f, 0.f}, {0.f, 0.f, 0.f, 0.f},
                           {0.f, 0.f, 0.f, 0.f}, {0.f, 0.f, 0.f, 0.f}};
        for (int k0 = 0; k0 < EMB_; k0 += 32) {
          __syncthreads();
#pragma unroll
          for (int p = 0; p < 8; ++p) {
            int li = t + p * 256;
            int kk = li & 31, m = li >> 5;
            int row = m0 + m;
            xcs[kk][m] = (row < SS) ? xcb[(size_t)row * EMB_ + k0 + kk] : 0.f;
            Ws[kk][m]  = Win[(size_t)(roff + m) * EMB_ + k0 + kk];
          }
          __syncthreads();
#pragma unroll
          for (int kk = 0; kk < 32; ++kk) {
            float4 av = *reinterpret_cast<const float4*>(&xcs[kk][ty * 4]);
            float4 wv = *reinterpret_cast<const float4*>(&Ws[kk][tx * 4]);
            float a[4] = {av.x, av.y, av.z, av.w};
            float w[4] = {wv.x, wv.y, wv.z, wv.w};
#pragma unroll
            for (int i = 0; i < 4; ++i)
#pragma unroll
              for (int j = 0; j < 4; ++j) acc[i][j] += a[i] * w[j];
          }
        }
        __syncthreads();
        float (*outT)[208] = (tgt == 0) ? qT : kT;
#pragma unroll
        for (int j = 0; j < 4; ++j) {
          int d = tx * 4 + j;
          float bb = bin[roff + d];
#pragma unroll
          for (int i = 0; i < 4; ++i) {
            int row = m0 + ty * 4 + i;
            if (row < SS) outT[d][row] = acc[i][j] + bb;
          }
        }
      }
    }
    __syncthreads();
    // ---- B1: scores S = q k^T / 8 -> Sb
    for (int i0 = 0; i0 < SS; i0 += 64)
      for (int j0 = 0; j0 < SS; j0 += 64) {
        float acc[4][4] = {{0.f, 0.f, 0.f, 0.f}, {0.f, 0.f, 0.f, 0.f},
                           {0.f, 0.f, 0.f, 0.f}, {0.f, 0.f, 0.f, 0.f}};
#pragma unroll 8
        for (int kk = 0; kk < 64; ++kk) {
          float4 av = *reinterpret_cast<const float4*>(&qT[kk][i0 + ty * 4]);
          float4 bv = *reinterpret_cast<const float4*>(&kT[kk][j0 + tx * 4]);
          float a[4] = {av.x, av.y, av.z, av.w};
          float w[4] = {bv.x, bv.y, bv.z, bv.w};
#pragma unroll
          for (int i = 0; i < 4; ++i)
#pragma unroll
            for (int j = 0; j < 4; ++j) acc[i][j] += a[i] * w[j];
        }
#pragma unroll
        for (int i = 0; i < 4; ++i) {
          int ri = i0 + ty * 4 + i;
          if (ri >= SS) continue;
          int cj = j0 + tx * 4;
          if (cj + 3 < SS) {
            float4 r;
            r.x = acc[i][0] * 0.125f; r.y = acc[i][1] * 0.125f;
            r.z = acc[i][2] * 0.125f; r.w = acc[i][3] * 0.125f;
            *reinterpret_cast<float4*>(&Sb[(size_t)ri * SS + cj]) = r;
          } else {
#pragma unroll
            for (int j = 0; j < 4; ++j)
              if (cj + j < SS) Sb[(size_t)ri * SS + cj + j] = acc[i][j] * 0.125f;
          }
        }
      }
    __syncthreads();
    // ---- B2: per-row max & 1/sumexp (wave per row)
    {
      int w = t >> 6, lane = t & 63;
      for (int i = w; i < SS; i += 4) {
        const float* r = &Sb[(size_t)i * SS];
        float s0 = r[lane], s1 = r[lane + 64], s2 = r[lane + 128];
        float s3 = (lane < 8) ? r[lane + 192] : -1e30f;
        float mx = fmaxf(fmaxf(s0, s1), fmaxf(s2, s3));
#pragma unroll
        for (int o = 32; o; o >>= 1) mx = fmaxf(mx, __shfl_xor(mx, o));
        float e = __expf(s0 - mx) + __expf(s1 - mx) + __expf(s2 - mx);
        if (lane < 8) e += __expf(s3 - mx);
#pragma unroll
        for (int o = 32; o; o >>= 1) e += __shfl_xor(e, o);
        if (lane == 0) { mrow[i] = mx; rl[i] = 1.0f / e; }
      }
    }
    __syncthreads();
    // ---- B3: column pass: attn-mean accumulate + column sums of p
    if (t < SS) {
      float cpj = 0.f;
      for (int i = 0; i < SS; ++i) {
        float p = __expf(Sb[(size_t)i * SS + t] - mrow[i]) * rl[i];
        cpj += p;
        Ab[(size_t)i * SS + t] += p * 0.125f;   // mean over 8 heads
      }
      cp[t] = cpj;
    }
    __syncthreads();
    // ---- B4: tvec = xc^T @ cp ; pooled[h-slice] = Wv @ tvec + bv*200
    for (int k = t; k < EMB_; k += 256) {
      float a = 0.f;
      for (int j = 0; j < SS; ++j) a += cp[j] * xcb[(size_t)j * EMB_ + k];
      tvec[k] = a;
    }
    __syncthreads();
    if (t < 64) {
      int vrow = 2 * EMB_ + h * 64 + t;
      const float* wr = &Win[(size_t)vrow * EMB_];
      float a = bin[vrow] * (float)SS;
      for (int k = 0; k < EMB_; ++k) a += wr[k] * tvec[k];
      pooled[(size_t)b * EMB_ + h * 64 + t] = a;
    }
    __syncthreads();
  }
}

// ---------------- readout: out = tanh((pooled/200 @ Wout^T + bout) @ finW + finb)
__global__ __launch_bounds__(256) void k_final(
    const float* __restrict__ pooled, const float* __restrict__ Wout,
    const float* __restrict__ bout, const float* __restrict__ finw,
    const float* __restrict__ finb, float* __restrict__ out) {
  const int b = blockIdx.x, t = threadIdx.x;
  __shared__ float pl[EMB_], po[EMB_];
  for (int k = t; k < EMB_; k += 256) pl[k] = pooled[(size_t)b * EMB_ + k] * (1.0f / (float)SS);
  __syncthreads();
  for (int e = t; e < EMB_; e += 256) {
    const float* wr = &Wout[(size_t)e * EMB_];
    float a = bout[e];
    for (int k = 0; k < EMB_; ++k) a += wr[k] * pl[k];
    po[e] = a;
  }
  __syncthreads();
  if (t < HD) {
    float a = finb[t];
    for (int e = 0; e < EMB_; ++e) a += po[e] * finw[(size_t)e * HD + t];
    out[(size_t)b * HD + t] = tanhf(a);
  }
}

// ---------------------------------------------------------------------------
extern "C" void kernel_launch(void* const* d_in, const int* in_sizes, int n_in,
                              void* d_out, int out_size, void* d_ws, size_t ws_size,
                              hipStream_t stream) {
  const float* x         = (const float*)d_in[0];
  const int*   ei        = (const int*)d_in[1];
  const float* gcn_w0    = (const float*)d_in[4];
  const float* gcn_w     = (const float*)d_in[5];
  const float* gcn_b     = (const float*)d_in[6];
  const float* lin1_w0   = (const float*)d_in[7];
  const float* lin1_w    = (const float*)d_in[8];
  const float* lin1_b    = (const float*)d_in[9];
  const float* lin2_w    = (const float*)d_in[10];
  const float* lin2_b    = (const float*)d_in[11];
  const float* sag_w1    = (const float*)d_in[12];
  const float* sag_w2    = (const float*)d_in[13];
  const float* sag_b     = (const float*)d_in[14];
  const float* mha_in_w  = (const float*)d_in[15];
  const float* mha_in_b  = (const float*)d_in[16];
  const float* mha_out_w = (const float*)d_in[17];
  const float* mha_out_b = (const float*)d_in[18];
  const float* fin_w     = (const float*)d_in[19];
  const float* fin_b     = (const float*)d_in[20];

  float* ws     = (float*)d_ws;
  float* dinv   = ws;                                  // 51,200
  float* Araw   = dinv + NT;                           // 10,240,000
  float* buf0   = Araw + (size_t)GB * SS * SS;         // 6,553,600  (xw / h)
  float* buf1   = buf0 + (size_t)NT * HD;              // 6,553,600  (x1)
  float* zbuf   = buf1 + (size_t)NT * HD;              // 6,553,600  (z)
  float* xcbuf  = zbuf + (size_t)NT * HD;              // 26,214,400 (xc)
  float* pooled = xcbuf + (size_t)NT * EMB_;           // 131,072

  float* outp = (float*)d_out;                         // [B,128]
  float* attn = outp + (size_t)GB * HD;                // [B,200,200]

  hipMemsetAsync(Araw, 0, (size_t)GB * SS * SS * sizeof(float), stream);
  hipMemsetAsync(attn, 0, (size_t)GB * SS * SS * sizeof(float), stream);

  k_build_A<<<NE_ / 256, 256, 0, stream>>>(ei, ei + NE_, Araw);
  k_dinv<<<NT / 4, 256, 0, stream>>>(Araw, dinv);

  for (int l = 0; l < NLAY; ++l) {
    const float* zin = (l == 0) ? x : zbuf;
    int k1 = (l == 0) ? KIN : HD;
    const float* gw  = (l == 0) ? gcn_w0  : gcn_w  + (size_t)(l - 1) * HD * HD;
    const float* l1w = (l == 0) ? lin1_w0 : lin1_w + (size_t)(l - 1) * 2 * HD * HD;
    // xw = zin @ gcn_w   (bias added after aggregation)
    k_gemm_node<<<(NT / 64) * 2, 256, 0, stream>>>(zin, k1, nullptr, 0, gw, nullptr, buf0, 0);
    // x1 = tanh( Â @ xw + gcn_b )
    k_gemm_agg<<<GB * 8, 256, 0, stream>>>(Araw, dinv, buf0, gcn_b + l * HD, buf1);
    // h = tanh( [zin | x1] @ lin1_w + lin1_b )
    k_gemm_node<<<(NT / 64) * 2, 256, 0, stream>>>(zin, k1, buf1, HD, l1w, lin1_b + l * HD, buf0, 1);
    // z = tanh( h @ lin2_w + lin2_b )
    k_gemm_node<<<(NT / 64) * 2, 256, 0, stream>>>(buf0, HD, nullptr, 0,
                                                   lin2_w + (size_t)l * HD * HD,
                                                   lin2_b + l * HD, zbuf, 1);
    // SAGPool -> xc[:, l*128:(l+1)*128]
    k_sag<<<GB, 256, 0, stream>>>(zbuf, Araw, sag_w1, sag_w2, sag_b, xcbuf, l);
  }

  k_mha<<<GB, 256, 0, stream>>>(xcbuf, mha_in_w, mha_in_b, Araw, attn, pooled);
  k_final<<<GB, 256, 0, stream>>>(pooled, mha_out_w, mha_out_b, fin_w, fin_b, outp);
}

// Round 4
// 4080.414 us; speedup vs baseline: 1.7071x; 1.7071x over previous
//
#include <hip/hip_runtime.h>
#include <hip/hip_fp16.h>

// ---------------------------------------------------------------------------
// GraphConv_8847632629923 : round 3
//   Round 2 structure. BUGFIX in k_attn: score-tile writes overflowed
//   Ss[32][208] at columns 208..255 (j0=192 tile), aliasing into the next
//   row's cols 0..47 and into aAcc[0][0..47] with deterministic zeros --
//   that (not Q/K precision) was the 4.6e-3 attn error, proven by the
//   bit-identical absmax across bf16 (r2) and fp16 (r3) runs.
//   Fix: guard jt=3 writes to cj<=204 (stays inside the 208 pad; pad cols
//   200..207 are never read). Q/K remain fp16.
// ---------------------------------------------------------------------------

#define GB   256          // batch (graphs)
#define SS   200          // nodes per graph
#define KIN  200          // input features
#define HD   128          // hidden
#define NLAY 4
#define NHD  8
#define TOPK 100
#define NT   (GB * SS)    // 51200 nodes
#define EPG_ 6400
#define NE_  (GB * EPG_)  // 1,638,400 edges
#define EMB_ 512

// ---------------- adjacency build ----------------
__global__ __launch_bounds__(256) void k_build_A(const int* __restrict__ src,
                                                 const int* __restrict__ dst,
                                                 float* __restrict__ A) {
  int e = blockIdx.x * 256 + threadIdx.x;
  if (e >= NE_) return;
  int d = dst[e], s = src[e];
  int b = d / SS;
  int dl = d - b * SS;
  int sl = s - b * SS;
  atomicAdd(&A[((size_t)b * SS + dl) * SS + sl], 1.0f);
}

// ---------------- dinv = rsqrt(in_deg + 1) ----------------
__global__ __launch_bounds__(256) void k_dinv(const float* __restrict__ A,
                                              float* __restrict__ dinv) {
  int node = blockIdx.x * 4 + (threadIdx.x >> 6);
  int lane = threadIdx.x & 63;
  const float* r = A + (size_t)node * SS;
  float v = r[lane] + r[lane + 64] + r[lane + 128];
  if (lane < 8) v += r[lane + 192];
#pragma unroll
  for (int o = 32; o; o >>= 1) v += __shfl_xor(v, o);
  if (lane == 0) dinv[node] = rsqrtf(v + 1.0f);
}

// ---------------- node GEMM: out[N,128] = act([in1|in2] @ W + bias) --------
__global__ __launch_bounds__(256) void k_gemm_node(
    const float* __restrict__ in1, int k1,
    const float* __restrict__ in2, int k2,        // optional, stride 128
    const float* __restrict__ W,                  // [k1+k2][128]
    const float* __restrict__ bias,               // [128] or null
    float* __restrict__ out, int doTanh) {
  const int row0 = (blockIdx.x >> 1) * 64;
  const int n0   = (blockIdx.x & 1) * 64;
  const int t  = threadIdx.x;
  const int tx = t & 15, ty = t >> 4;
  const int K = k1 + k2;
  __shared__ __align__(16) float As[32][68];
  __shared__ __align__(16) float Bs[32][68];
  float acc[4][4] = {{0.f, 0.f, 0.f, 0.f}, {0.f, 0.f, 0.f, 0.f},
                     {0.f, 0.f, 0.f, 0.f}, {0.f, 0.f, 0.f, 0.f}};
  for (int k0 = 0; k0 < K; k0 += 32) {
    __syncthreads();
#pragma unroll
    for (int p = 0; p < 8; ++p) {
      int li = t + p * 256;
      int kk = li & 31, m = li >> 5;
      int kg = k0 + kk;
      int row = row0 + m;
      float v = 0.f;
      if (kg < k1)     v = in1[(size_t)row * k1 + kg];
      else if (kg < K) v = in2[(size_t)row * HD + (kg - k1)];
      As[kk][m] = v;
      int n = li & 63, kb = li >> 6;
      int kg2 = k0 + kb;
      Bs[kb][n] = (kg2 < K) ? W[(size_t)kg2 * HD + n0 + n] : 0.f;
    }
    __syncthreads();
#pragma unroll
    for (int kk = 0; kk < 32; ++kk) {
      float4 av = *reinterpret_cast<const float4*>(&As[kk][ty * 4]);
      float4 wv = *reinterpret_cast<const float4*>(&Bs[kk][tx * 4]);
      float a[4] = {av.x, av.y, av.z, av.w};
      float w[4] = {wv.x, wv.y, wv.z, wv.w};
#pragma unroll
      for (int i = 0; i < 4; ++i)
#pragma unroll
        for (int j = 0; j < 4; ++j) acc[i][j] += a[i] * w[j];
    }
  }
#pragma unroll
  for (int i = 0; i < 4; ++i) {
    int row = row0 + ty * 4 + i;
    int c = n0 + tx * 4;
    float4 r;
    r.x = acc[i][0] + (bias ? bias[c + 0] : 0.f);
    r.y = acc[i][1] + (bias ? bias[c + 1] : 0.f);
    r.z = acc[i][2] + (bias ? bias[c + 2] : 0.f);
    r.w = acc[i][3] + (bias ? bias[c + 3] : 0.f);
    if (doTanh) { r.x = tanhf(r.x); r.y = tanhf(r.y); r.z = tanhf(r.z); r.w = tanhf(r.w); }
    *reinterpret_cast<float4*>(&out[(size_t)row * HD + c]) = r;
  }
}

// --------- GCN aggregation: x1 = tanh( Â @ xw + b ), Â normalized on load ---
__global__ __launch_bounds__(256) void k_gemm_agg(
    const float* __restrict__ A, const float* __restrict__ dinv,
    const float* __restrict__ xw, const float* __restrict__ bias,
    float* __restrict__ out) {
  const int b    = blockIdx.x >> 3;
  const int row0 = ((blockIdx.x >> 1) & 3) * 64;
  const int n0   = (blockIdx.x & 1) * 64;
  const int t  = threadIdx.x;
  const int tx = t & 15, ty = t >> 4;
  const float* Ab = A + (size_t)b * SS * SS;
  const float* dv = dinv + b * SS;
  __shared__ __align__(16) float As[32][68];
  __shared__ __align__(16) float Bs[32][68];
  float acc[4][4] = {{0.f, 0.f, 0.f, 0.f}, {0.f, 0.f, 0.f, 0.f},
                     {0.f, 0.f, 0.f, 0.f}, {0.f, 0.f, 0.f, 0.f}};
  for (int k0 = 0; k0 < SS; k0 += 32) {
    __syncthreads();
#pragma unroll
    for (int p = 0; p < 8; ++p) {
      int li = t + p * 256;
      int kk = li & 31, m = li >> 5;
      int d = row0 + m;
      int sg = k0 + kk;
      float v = 0.f;
      if (d < SS && sg < SS) {
        v = Ab[(size_t)d * SS + sg];
        if (d == sg) v += 1.0f;               // self-loop
        v *= dv[d] * dv[sg];                  // D^-1/2 (A+I) D^-1/2
      }
      As[kk][m] = v;
      int n = li & 63, kb = li >> 6;
      int sg2 = k0 + kb;
      Bs[kb][n] = (sg2 < SS) ? xw[((size_t)b * SS + sg2) * HD + n0 + n] : 0.f;
    }
    __syncthreads();
#pragma unroll
    for (int kk = 0; kk < 32; ++kk) {
      float4 av = *reinterpret_cast<const float4*>(&As[kk][ty * 4]);
      float4 wv = *reinterpret_cast<const float4*>(&Bs[kk][tx * 4]);
      float a[4] = {av.x, av.y, av.z, av.w};
      float w[4] = {wv.x, wv.y, wv.z, wv.w};
#pragma unroll
      for (int i = 0; i < 4; ++i)
#pragma unroll
        for (int j = 0; j < 4; ++j) acc[i][j] += a[i] * w[j];
    }
  }
#pragma unroll
  for (int i = 0; i < 4; ++i) {
    int row = row0 + ty * 4 + i;
    if (row >= SS) continue;
    int c = n0 + tx * 4;
    float4 r;
    r.x = tanhf(acc[i][0] + bias[c + 0]);
    r.y = tanhf(acc[i][1] + bias[c + 1]);
    r.z = tanhf(acc[i][2] + bias[c + 2]);
    r.w = tanhf(acc[i][3] + bias[c + 3]);
    *reinterpret_cast<float4*>(&out[((size_t)b * SS + row) * HD + c]) = r;
  }
}

// ---------------- SAGPool: score, top-k select, padded write ----------------
__global__ __launch_bounds__(256) void k_sag(
    const float* __restrict__ z, const float* __restrict__ A,
    const float* __restrict__ w1, const float* __restrict__ w2,
    const float* __restrict__ sb, float* __restrict__ xc, int layer) {
  const int b = blockIdx.x, t = threadIdx.x;
  __shared__ float w1s[HD], w2s[HD];
  __shared__ float zw1[SS], sc[SS], fac[SS];
  if (t < HD) { w1s[t] = w1[t]; w2s[t] = w2[t]; }
  __syncthreads();
  float a2 = 0.f;
  if (t < SS) {
    const float4* zr = reinterpret_cast<const float4*>(&z[((size_t)b * SS + t) * HD]);
    float a1 = 0.f;
#pragma unroll
    for (int q = 0; q < HD / 4; ++q) {
      float4 v = zr[q];
      a1 += v.x * w1s[4 * q] + v.y * w1s[4 * q + 1] + v.z * w1s[4 * q + 2] + v.w * w1s[4 * q + 3];
      a2 += v.x * w2s[4 * q] + v.y * w2s[4 * q + 1] + v.z * w2s[4 * q + 2] + v.w * w2s[4 * q + 3];
    }
    zw1[t] = a1;
  }
  __syncthreads();
  if (t < SS) {
    float s = sb[0] + a2;
    const float4* ar = reinterpret_cast<const float4*>(&A[((size_t)b * SS + t) * SS]);
#pragma unroll 5
    for (int q = 0; q < SS / 4; ++q) {
      float4 v = ar[q];
      s += v.x * zw1[4 * q] + v.y * zw1[4 * q + 1] + v.z * zw1[4 * q + 2] + v.w * zw1[4 * q + 3];
    }
    sc[t] = s;
  }
  __syncthreads();
  if (t < SS) {
    float si = sc[t];
    int cnt = 0;
    for (int j = 0; j < SS; ++j) {
      float sj = sc[j];
      cnt += (sj > si || (sj == si && j < t)) ? 1 : 0;
    }
    fac[t] = (cnt < TOPK) ? tanhf(si) : 0.f;
  }
  __syncthreads();
  for (int idx = t; idx < SS * HD; idx += 256) {
    int row = idx >> 7, c = idx & 127;
    xc[((size_t)b * SS + row) * EMB_ + layer * HD + c] =
        fac[row] * z[((size_t)b * SS + row) * HD + c];
  }
}

// ------------- k_proj: QK[N,1024](fp16) = xc @ [Wq|Wk]^T + b ----------------
__global__ __launch_bounds__(256) void k_proj(
    const float* __restrict__ xc, const float* __restrict__ Win,
    const float* __restrict__ bin, __half* __restrict__ QKh) {
  const int row0 = (blockIdx.x >> 4) * 64;
  const int n0   = (blockIdx.x & 15) * 64;
  const int t  = threadIdx.x;
  const int tx = t & 15, ty = t >> 4;
  __shared__ __align__(16) float As[32][68];
  __shared__ __align__(16) float Bs[32][68];
  float acc[4][4] = {{0.f, 0.f, 0.f, 0.f}, {0.f, 0.f, 0.f, 0.f},
                     {0.f, 0.f, 0.f, 0.f}, {0.f, 0.f, 0.f, 0.f}};
  for (int k0 = 0; k0 < EMB_; k0 += 32) {
    __syncthreads();
#pragma unroll
    for (int p = 0; p < 8; ++p) {
      int li = t + p * 256;
      int kk = li & 31, m = li >> 5;
      As[kk][m] = xc[(size_t)(row0 + m) * EMB_ + k0 + kk];
      Bs[kk][m] = Win[(size_t)(n0 + m) * EMB_ + k0 + kk];   // W^T on the fly
    }
    __syncthreads();
#pragma unroll
    for (int kk = 0; kk < 32; ++kk) {
      float4 av = *reinterpret_cast<const float4*>(&As[kk][ty * 4]);
      float4 wv = *reinterpret_cast<const float4*>(&Bs[kk][tx * 4]);
      float a[4] = {av.x, av.y, av.z, av.w};
      float w[4] = {wv.x, wv.y, wv.z, wv.w};
#pragma unroll
      for (int i = 0; i < 4; ++i)
#pragma unroll
        for (int j = 0; j < 4; ++j) acc[i][j] += a[i] * w[j];
    }
  }
#pragma unroll
  for (int i = 0; i < 4; ++i) {
    int row = row0 + ty * 4 + i;
    int c = n0 + tx * 4;
    __half2 r01, r23;
    r01 = __floats2half2_rn(acc[i][0] + bin[c + 0], acc[i][1] + bin[c + 1]);
    r23 = __floats2half2_rn(acc[i][2] + bin[c + 2], acc[i][3] + bin[c + 3]);
    *reinterpret_cast<__half2*>(&QKh[(size_t)row * 1024 + c + 0]) = r01;
    *reinterpret_cast<__half2*>(&QKh[(size_t)row * 1024 + c + 2]) = r23;
  }
}

// ------------- k_attn: per (graph, 32-row tile), all heads ------------------
__global__ __launch_bounds__(256) void k_attn(
    const __half* __restrict__ QKh,
    float* __restrict__ cpbuf,          // [B][8][200], pre-zeroed
    float* __restrict__ attn) {         // [B][200][200]
  const int b  = blockIdx.x / 7;
  const int it = blockIdx.x % 7;
  const int i0 = it * 32;
  const int rows = (SS - i0 >= 32) ? 32 : (SS - i0);   // 32 or 8
  const int t = threadIdx.x;
  const int tx = t & 15, ty = t >> 4;
  const int wv = t >> 6, lane = t & 63;
  __shared__ __align__(16) float qT[64][33];
  __shared__ __align__(16) float kT[64][68];
  __shared__ __align__(16) float Ss[32][208];
  __shared__ __align__(16) float aAcc[32][208];
  float* aflat = &aAcc[0][0];
  for (int idx = t; idx < 32 * 208; idx += 256) aflat[idx] = 0.f;

  for (int h = 0; h < NHD; ++h) {
    __syncthreads();
    // stage q tile [rows<=32][64] transposed -> qT[d][i]
#pragma unroll
    for (int p = 0; p < 8; ++p) {
      int li = t + p * 256;
      int d = li & 63, i = li >> 6;
      int gi = i0 + i;
      float v = 0.f;
      if (gi < SS) v = __half2float(QKh[(size_t)(b * SS + gi) * 1024 + h * 64 + d]);
      qT[d][i] = v;
    }
    for (int jt = 0; jt < 4; ++jt) {
      const int j0 = jt * 64;
      __syncthreads();
#pragma unroll
      for (int p = 0; p < 16; ++p) {
        int li = t + p * 256;
        int d = li & 63, j = li >> 6;
        int gj = j0 + j;
        float v = 0.f;
        if (gj < SS) v = __half2float(QKh[(size_t)(b * SS + gj) * 1024 + 512 + h * 64 + d]);
        kT[d][j] = v;
      }
      __syncthreads();
      float acc[2][4] = {{0.f, 0.f, 0.f, 0.f}, {0.f, 0.f, 0.f, 0.f}};
#pragma unroll 16
      for (int kk = 0; kk < 64; ++kk) {
        float a0 = qT[kk][ty * 2];
        float a1 = qT[kk][ty * 2 + 1];
        float4 kv = *reinterpret_cast<const float4*>(&kT[kk][tx * 4]);
        acc[0][0] += a0 * kv.x; acc[0][1] += a0 * kv.y;
        acc[0][2] += a0 * kv.z; acc[0][3] += a0 * kv.w;
        acc[1][0] += a1 * kv.x; acc[1][1] += a1 * kv.y;
        acc[1][2] += a1 * kv.z; acc[1][3] += a1 * kv.w;
      }
      // BUGFIX: only write columns that stay inside the 208-wide row.
      // (cols 200..207 are pad, never read; cols >=208 previously aliased
      //  into Ss[r+1][0..47] / aAcc[0][0..47] with zeros.)
      {
        int cj = j0 + tx * 4;
        if (cj <= 204) {
#pragma unroll
          for (int r = 0; r < 2; ++r) {
            float4 sv;
            sv.x = acc[r][0] * 0.125f; sv.y = acc[r][1] * 0.125f;
            sv.z = acc[r][2] * 0.125f; sv.w = acc[r][3] * 0.125f;
            *reinterpret_cast<float4*>(&Ss[ty * 2 + r][cj]) = sv;
          }
        }
      }
    }
    __syncthreads();
    // softmax per row (wave per row) + attn-mean accumulate
    for (int r = wv; r < rows; r += 4) {
      float* srow = &Ss[r][0];
      float s0 = srow[lane], s1 = srow[lane + 64], s2 = srow[lane + 128];
      float s3 = (lane < 8) ? srow[lane + 192] : -1e30f;
      float mx = fmaxf(fmaxf(s0, s1), fmaxf(s2, s3));
#pragma unroll
      for (int o = 32; o; o >>= 1) mx = fmaxf(mx, __shfl_xor(mx, o));
      float e0 = __expf(s0 - mx), e1 = __expf(s1 - mx), e2 = __expf(s2 - mx);
      float e3 = (lane < 8) ? __expf(s3 - mx) : 0.f;
      float sum = e0 + e1 + e2 + e3;
#pragma unroll
      for (int o = 32; o; o >>= 1) sum += __shfl_xor(sum, o);
      float rl = 1.0f / sum;
      e0 *= rl; e1 *= rl; e2 *= rl;
      srow[lane] = e0; srow[lane + 64] = e1; srow[lane + 128] = e2;
      aAcc[r][lane]       += e0 * 0.125f;
      aAcc[r][lane + 64]  += e1 * 0.125f;
      aAcc[r][lane + 128] += e2 * 0.125f;
      if (lane < 8) {
        e3 *= rl;
        srow[lane + 192] = e3;
        aAcc[r][lane + 192] += e3 * 0.125f;
      }
    }
    __syncthreads();
    // per-head column sums -> cp
    if (t < SS) {
      float s = 0.f;
      for (int i = 0; i < rows; ++i) s += Ss[i][t];
      atomicAdd(&cpbuf[((size_t)b * NHD + h) * SS + t], s);
    }
    __syncthreads();
  }
  __syncthreads();
  for (int idx = t; idx < rows * 50; idx += 256) {
    int i = idx / 50, q = idx - i * 50;
    *reinterpret_cast<float4*>(&attn[((size_t)b * SS + i0 + i) * SS + q * 4]) =
        *reinterpret_cast<const float4*>(&aAcc[i][q * 4]);
  }
}

// ------------- k_pool: tvec_h = cp_h^T @ xc ; pooled = Wv tvec + bv*200 -----
__global__ __launch_bounds__(256) void k_pool(
    const float* __restrict__ xc, const float* __restrict__ cpbuf,
    const float* __restrict__ Win, const float* __restrict__ bin,
    float* __restrict__ pooled) {
  const int b = blockIdx.x, t = threadIdx.x;
  __shared__ float cps[NHD][SS];
  __shared__ float tvs[NHD][EMB_];
  for (int idx = t; idx < NHD * SS; idx += 256) {
    int h = idx / SS, j = idx - h * SS;
    cps[h][j] = cpbuf[((size_t)b * NHD + h) * SS + j];
  }
  __syncthreads();
  const float* xcb = xc + (size_t)b * SS * EMB_;
  float a0[NHD] = {0.f}, a1[NHD] = {0.f};
  for (int j = 0; j < SS; ++j) {
    float x0 = xcb[(size_t)j * EMB_ + t];
    float x1 = xcb[(size_t)j * EMB_ + t + 256];
#pragma unroll
    for (int h = 0; h < NHD; ++h) {
      float c = cps[h][j];
      a0[h] += c * x0; a1[h] += c * x1;
    }
  }
#pragma unroll
  for (int h = 0; h < NHD; ++h) { tvs[h][t] = a0[h]; tvs[h][t + 256] = a1[h]; }
  __syncthreads();
  const int wv = t >> 6, lane = t & 63;
  for (int e = wv; e < EMB_; e += 4) {
    int h = e >> 6;
    const float* wr = Win + (size_t)(2 * EMB_ + e) * EMB_;
    float s = 0.f;
#pragma unroll
    for (int q = 0; q < 8; ++q) s += wr[lane + q * 64] * tvs[h][lane + q * 64];
#pragma unroll
    for (int o = 32; o; o >>= 1) s += __shfl_xor(s, o);
    if (lane == 0) pooled[(size_t)b * EMB_ + e] = bin[2 * EMB_ + e] * (float)SS + s;
  }
}

// ---------------- readout ----------------
__global__ __launch_bounds__(256) void k_final(
    const float* __restrict__ pooled, const float* __restrict__ Wout,
    const float* __restrict__ bout, const float* __restrict__ finw,
    const float* __restrict__ finb, float* __restrict__ out) {
  const int b = blockIdx.x, t = threadIdx.x;
  __shared__ float pl[EMB_], po[EMB_];
  for (int k = t; k < EMB_; k += 256) pl[k] = pooled[(size_t)b * EMB_ + k] * (1.0f / (float)SS);
  __syncthreads();
  for (int e = t; e < EMB_; e += 256) {
    const float* wr = &Wout[(size_t)e * EMB_];
    float a = bout[e];
    for (int k = 0; k < EMB_; ++k) a += wr[k] * pl[k];
    po[e] = a;
  }
  __syncthreads();
  if (t < HD) {
    float a = finb[t];
    for (int e = 0; e < EMB_; ++e) a += po[e] * finw[(size_t)e * HD + t];
    out[(size_t)b * HD + t] = tanhf(a);
  }
}

// ---------------------------------------------------------------------------
extern "C" void kernel_launch(void* const* d_in, const int* in_sizes, int n_in,
                              void* d_out, int out_size, void* d_ws, size_t ws_size,
                              hipStream_t stream) {
  const float* x         = (const float*)d_in[0];
  const int*   ei        = (const int*)d_in[1];
  const float* gcn_w0    = (const float*)d_in[4];
  const float* gcn_w     = (const float*)d_in[5];
  const float* gcn_b     = (const float*)d_in[6];
  const float* lin1_w0   = (const float*)d_in[7];
  const float* lin1_w    = (const float*)d_in[8];
  const float* lin1_b    = (const float*)d_in[9];
  const float* lin2_w    = (const float*)d_in[10];
  const float* lin2_b    = (const float*)d_in[11];
  const float* sag_w1    = (const float*)d_in[12];
  const float* sag_w2    = (const float*)d_in[13];
  const float* sag_b     = (const float*)d_in[14];
  const float* mha_in_w  = (const float*)d_in[15];
  const float* mha_in_b  = (const float*)d_in[16];
  const float* mha_out_w = (const float*)d_in[17];
  const float* mha_out_b = (const float*)d_in[18];
  const float* fin_w     = (const float*)d_in[19];
  const float* fin_b     = (const float*)d_in[20];

  float* ws     = (float*)d_ws;
  float* dinv   = ws;                                  // 51,200
  float* Araw   = dinv + NT;                           // 10,240,000
  float* buf0   = Araw + (size_t)GB * SS * SS;         // 6,553,600
  float* buf1   = buf0 + (size_t)NT * HD;              // 6,553,600
  float* zbuf   = buf1 + (size_t)NT * HD;              // 6,553,600
  float* xcbuf  = zbuf + (size_t)NT * HD;              // 26,214,400 (xc)
  float* pooled = xcbuf + (size_t)NT * EMB_;           // 131,072
  // QK (fp16) overlays [Araw .. zbuf) once the GCN layers are done:
  __half* QKh  = (__half*)Araw;                        // 52,428,800 halves
  float* cpbuf = Araw + 26214400;                      // 409,600 floats (tail of overlay)

  float* outp = (float*)d_out;                         // [B,128]
  float* attn = outp + (size_t)GB * HD;                // [B,200,200]

  hipMemsetAsync(Araw, 0, (size_t)GB * SS * SS * sizeof(float), stream);

  k_build_A<<<NE_ / 256, 256, 0, stream>>>(ei, ei + NE_, Araw);
  k_dinv<<<NT / 4, 256, 0, stream>>>(Araw, dinv);

  for (int l = 0; l < NLAY; ++l) {
    const float* zin = (l == 0) ? x : zbuf;
    int k1 = (l == 0) ? KIN : HD;
    const float* gw  = (l == 0) ? gcn_w0  : gcn_w  + (size_t)(l - 1) * HD * HD;
    const float* l1w = (l == 0) ? lin1_w0 : lin1_w + (size_t)(l - 1) * 2 * HD * HD;
    k_gemm_node<<<(NT / 64) * 2, 256, 0, stream>>>(zin, k1, nullptr, 0, gw, nullptr, buf0, 0);
    k_gemm_agg<<<GB * 8, 256, 0, stream>>>(Araw, dinv, buf0, gcn_b + l * HD, buf1);
    k_gemm_node<<<(NT / 64) * 2, 256, 0, stream>>>(zin, k1, buf1, HD, l1w, lin1_b + l * HD, buf0, 1);
    k_gemm_node<<<(NT / 64) * 2, 256, 0, stream>>>(buf0, HD, nullptr, 0,
                                                   lin2_w + (size_t)l * HD * HD,
                                                   lin2_b + l * HD, zbuf, 1);
    k_sag<<<GB, 256, 0, stream>>>(zbuf, Araw, sag_w1, sag_w2, sag_b, xcbuf, l);
  }

  // ---- MHA ----
  hipMemsetAsync(cpbuf, 0, (size_t)GB * NHD * SS * sizeof(float), stream);
  k_proj<<<(NT / 64) * 16, 256, 0, stream>>>(xcbuf, mha_in_w, mha_in_b, QKh);
  k_attn<<<GB * 7, 256, 0, stream>>>(QKh, cpbuf, attn);
  k_pool<<<GB, 256, 0, stream>>>(xcbuf, cpbuf, mha_in_w, mha_in_b, pooled);
  k_final<<<GB, 256, 0, stream>>>(pooled, mha_out_w, mha_out_b, fin_w, fin_b, outp);
}

// Round 5
// 3623.549 us; speedup vs baseline: 1.9223x; 1.1261x over previous
//
#include <hip/hip_runtime.h>
#include <hip/hip_fp16.h>

// ---------------------------------------------------------------------------
// GraphConv_8847632629923 : round 4
//   k_attn rewritten on MFMA (mfma_f32_16x16x32_f16):
//     block = (graph, 16-row tile), 3328 blocks, 45.8 KB LDS -> 3 blocks/CU.
//     QK^T via matrix cores (Q/K already fp16; fp32 accumulation as before).
//     attn-mean kept in registers (13/thread), coalesced final store.
//   Everything else identical to round 3 (passing, absmax 1.2e-4).
// ---------------------------------------------------------------------------

#define GB   256          // batch (graphs)
#define SS   200          // nodes per graph
#define KIN  200          // input features
#define HD   128          // hidden
#define NLAY 4
#define NHD  8
#define TOPK 100
#define NT   (GB * SS)    // 51200 nodes
#define EPG_ 6400
#define NE_  (GB * EPG_)  // 1,638,400 edges
#define EMB_ 512

typedef _Float16 half8 __attribute__((ext_vector_type(8)));
typedef float floatx4 __attribute__((ext_vector_type(4)));

// ---------------- adjacency build ----------------
__global__ __launch_bounds__(256) void k_build_A(const int* __restrict__ src,
                                                 const int* __restrict__ dst,
                                                 float* __restrict__ A) {
  int e = blockIdx.x * 256 + threadIdx.x;
  if (e >= NE_) return;
  int d = dst[e], s = src[e];
  int b = d / SS;
  int dl = d - b * SS;
  int sl = s - b * SS;
  atomicAdd(&A[((size_t)b * SS + dl) * SS + sl], 1.0f);
}

// ---------------- dinv = rsqrt(in_deg + 1) ----------------
__global__ __launch_bounds__(256) void k_dinv(const float* __restrict__ A,
                                              float* __restrict__ dinv) {
  int node = blockIdx.x * 4 + (threadIdx.x >> 6);
  int lane = threadIdx.x & 63;
  const float* r = A + (size_t)node * SS;
  float v = r[lane] + r[lane + 64] + r[lane + 128];
  if (lane < 8) v += r[lane + 192];
#pragma unroll
  for (int o = 32; o; o >>= 1) v += __shfl_xor(v, o);
  if (lane == 0) dinv[node] = rsqrtf(v + 1.0f);
}

// ---------------- node GEMM: out[N,128] = act([in1|in2] @ W + bias) --------
__global__ __launch_bounds__(256) void k_gemm_node(
    const float* __restrict__ in1, int k1,
    const float* __restrict__ in2, int k2,        // optional, stride 128
    const float* __restrict__ W,                  // [k1+k2][128]
    const float* __restrict__ bias,               // [128] or null
    float* __restrict__ out, int doTanh) {
  const int row0 = (blockIdx.x >> 1) * 64;
  const int n0   = (blockIdx.x & 1) * 64;
  const int t  = threadIdx.x;
  const int tx = t & 15, ty = t >> 4;
  const int K = k1 + k2;
  __shared__ __align__(16) float As[32][68];
  __shared__ __align__(16) float Bs[32][68];
  float acc[4][4] = {{0.f, 0.f, 0.f, 0.f}, {0.f, 0.f, 0.f, 0.f},
                     {0.f, 0.f, 0.f, 0.f}, {0.f, 0.f, 0.f, 0.f}};
  for (int k0 = 0; k0 < K; k0 += 32) {
    __syncthreads();
#pragma unroll
    for (int p = 0; p < 8; ++p) {
      int li = t + p * 256;
      int kk = li & 31, m = li >> 5;
      int kg = k0 + kk;
      int row = row0 + m;
      float v = 0.f;
      if (kg < k1)     v = in1[(size_t)row * k1 + kg];
      else if (kg < K) v = in2[(size_t)row * HD + (kg - k1)];
      As[kk][m] = v;
      int n = li & 63, kb = li >> 6;
      int kg2 = k0 + kb;
      Bs[kb][n] = (kg2 < K) ? W[(size_t)kg2 * HD + n0 + n] : 0.f;
    }
    __syncthreads();
#pragma unroll
    for (int kk = 0; kk < 32; ++kk) {
      float4 av = *reinterpret_cast<const float4*>(&As[kk][ty * 4]);
      float4 wv = *reinterpret_cast<const float4*>(&Bs[kk][tx * 4]);
      float a[4] = {av.x, av.y, av.z, av.w};
      float w[4] = {wv.x, wv.y, wv.z, wv.w};
#pragma unroll
      for (int i = 0; i < 4; ++i)
#pragma unroll
        for (int j = 0; j < 4; ++j) acc[i][j] += a[i] * w[j];
    }
  }
#pragma unroll
  for (int i = 0; i < 4; ++i) {
    int row = row0 + ty * 4 + i;
    int c = n0 + tx * 4;
    float4 r;
    r.x = acc[i][0] + (bias ? bias[c + 0] : 0.f);
    r.y = acc[i][1] + (bias ? bias[c + 1] : 0.f);
    r.z = acc[i][2] + (bias ? bias[c + 2] : 0.f);
    r.w = acc[i][3] + (bias ? bias[c + 3] : 0.f);
    if (doTanh) { r.x = tanhf(r.x); r.y = tanhf(r.y); r.z = tanhf(r.z); r.w = tanhf(r.w); }
    *reinterpret_cast<float4*>(&out[(size_t)row * HD + c]) = r;
  }
}

// --------- GCN aggregation: x1 = tanh( Â @ xw + b ), Â normalized on load ---
__global__ __launch_bounds__(256) void k_gemm_agg(
    const float* __restrict__ A, const float* __restrict__ dinv,
    const float* __restrict__ xw, const float* __restrict__ bias,
    float* __restrict__ out) {
  const int b    = blockIdx.x >> 3;
  const int row0 = ((blockIdx.x >> 1) & 3) * 64;
  const int n0   = (blockIdx.x & 1) * 64;
  const int t  = threadIdx.x;
  const int tx = t & 15, ty = t >> 4;
  const float* Ab = A + (size_t)b * SS * SS;
  const float* dv = dinv + b * SS;
  __shared__ __align__(16) float As[32][68];
  __shared__ __align__(16) float Bs[32][68];
  float acc[4][4] = {{0.f, 0.f, 0.f, 0.f}, {0.f, 0.f, 0.f, 0.f},
                     {0.f, 0.f, 0.f, 0.f}, {0.f, 0.f, 0.f, 0.f}};
  for (int k0 = 0; k0 < SS; k0 += 32) {
    __syncthreads();
#pragma unroll
    for (int p = 0; p < 8; ++p) {
      int li = t + p * 256;
      int kk = li & 31, m = li >> 5;
      int d = row0 + m;
      int sg = k0 + kk;
      float v = 0.f;
      if (d < SS && sg < SS) {
        v = Ab[(size_t)d * SS + sg];
        if (d == sg) v += 1.0f;               // self-loop
        v *= dv[d] * dv[sg];                  // D^-1/2 (A+I) D^-1/2
      }
      As[kk][m] = v;
      int n = li & 63, kb = li >> 6;
      int sg2 = k0 + kb;
      Bs[kb][n] = (sg2 < SS) ? xw[((size_t)b * SS + sg2) * HD + n0 + n] : 0.f;
    }
    __syncthreads();
#pragma unroll
    for (int kk = 0; kk < 32; ++kk) {
      float4 av = *reinterpret_cast<const float4*>(&As[kk][ty * 4]);
      float4 wv = *reinterpret_cast<const float4*>(&Bs[kk][tx * 4]);
      float a[4] = {av.x, av.y, av.z, av.w};
      float w[4] = {wv.x, wv.y, wv.z, wv.w};
#pragma unroll
      for (int i = 0; i < 4; ++i)
#pragma unroll
        for (int j = 0; j < 4; ++j) acc[i][j] += a[i] * w[j];
    }
  }
#pragma unroll
  for (int i = 0; i < 4; ++i) {
    int row = row0 + ty * 4 + i;
    if (row >= SS) continue;
    int c = n0 + tx * 4;
    float4 r;
    r.x = tanhf(acc[i][0] + bias[c + 0]);
    r.y = tanhf(acc[i][1] + bias[c + 1]);
    r.z = tanhf(acc[i][2] + bias[c + 2]);
    r.w = tanhf(acc[i][3] + bias[c + 3]);
    *reinterpret_cast<float4*>(&out[((size_t)b * SS + row) * HD + c]) = r;
  }
}

// ---------------- SAGPool: score, top-k select, padded write ----------------
__global__ __launch_bounds__(256) void k_sag(
    const float* __restrict__ z, const float* __restrict__ A,
    const float* __restrict__ w1, const float* __restrict__ w2,
    const float* __restrict__ sb, float* __restrict__ xc, int layer) {
  const int b = blockIdx.x, t = threadIdx.x;
  __shared__ float w1s[HD], w2s[HD];
  __shared__ float zw1[SS], sc[SS], fac[SS];
  if (t < HD) { w1s[t] = w1[t]; w2s[t] = w2[t]; }
  __syncthreads();
  float a2 = 0.f;
  if (t < SS) {
    const float4* zr = reinterpret_cast<const float4*>(&z[((size_t)b * SS + t) * HD]);
    float a1 = 0.f;
#pragma unroll
    for (int q = 0; q < HD / 4; ++q) {
      float4 v = zr[q];
      a1 += v.x * w1s[4 * q] + v.y * w1s[4 * q + 1] + v.z * w1s[4 * q + 2] + v.w * w1s[4 * q + 3];
      a2 += v.x * w2s[4 * q] + v.y * w2s[4 * q + 1] + v.z * w2s[4 * q + 2] + v.w * w2s[4 * q + 3];
    }
    zw1[t] = a1;
  }
  __syncthreads();
  if (t < SS) {
    float s = sb[0] + a2;
    const float4* ar = reinterpret_cast<const float4*>(&A[((size_t)b * SS + t) * SS]);
#pragma unroll 5
    for (int q = 0; q < SS / 4; ++q) {
      float4 v = ar[q];
      s += v.x * zw1[4 * q] + v.y * zw1[4 * q + 1] + v.z * zw1[4 * q + 2] + v.w * zw1[4 * q + 3];
    }
    sc[t] = s;
  }
  __syncthreads();
  if (t < SS) {
    float si = sc[t];
    int cnt = 0;
    for (int j = 0; j < SS; ++j) {
      float sj = sc[j];
      cnt += (sj > si || (sj == si && j < t)) ? 1 : 0;
    }
    fac[t] = (cnt < TOPK) ? tanhf(si) : 0.f;
  }
  __syncthreads();
  for (int idx = t; idx < SS * HD; idx += 256) {
    int row = idx >> 7, c = idx & 127;
    xc[((size_t)b * SS + row) * EMB_ + layer * HD + c] =
        fac[row] * z[((size_t)b * SS + row) * HD + c];
  }
}

// ------------- k_proj: QK[N,1024](fp16) = xc @ [Wq|Wk]^T + b ----------------
__global__ __launch_bounds__(256) void k_proj(
    const float* __restrict__ xc, const float* __restrict__ Win,
    const float* __restrict__ bin, __half* __restrict__ QKh) {
  const int row0 = (blockIdx.x >> 4) * 64;
  const int n0   = (blockIdx.x & 15) * 64;
  const int t  = threadIdx.x;
  const int tx = t & 15, ty = t >> 4;
  __shared__ __align__(16) float As[32][68];
  __shared__ __align__(16) float Bs[32][68];
  float acc[4][4] = {{0.f, 0.f, 0.f, 0.f}, {0.f, 0.f, 0.f, 0.f},
                     {0.f, 0.f, 0.f, 0.f}, {0.f, 0.f, 0.f, 0.f}};
  for (int k0 = 0; k0 < EMB_; k0 += 32) {
    __syncthreads();
#pragma unroll
    for (int p = 0; p < 8; ++p) {
      int li = t + p * 256;
      int kk = li & 31, m = li >> 5;
      As[kk][m] = xc[(size_t)(row0 + m) * EMB_ + k0 + kk];
      Bs[kk][m] = Win[(size_t)(n0 + m) * EMB_ + k0 + kk];   // W^T on the fly
    }
    __syncthreads();
#pragma unroll
    for (int kk = 0; kk < 32; ++kk) {
      float4 av = *reinterpret_cast<const float4*>(&As[kk][ty * 4]);
      float4 wv = *reinterpret_cast<const float4*>(&Bs[kk][tx * 4]);
      float a[4] = {av.x, av.y, av.z, av.w};
      float w[4] = {wv.x, wv.y, wv.z, wv.w};
#pragma unroll
      for (int i = 0; i < 4; ++i)
#pragma unroll
        for (int j = 0; j < 4; ++j) acc[i][j] += a[i] * w[j];
    }
  }
#pragma unroll
  for (int i = 0; i < 4; ++i) {
    int row = row0 + ty * 4 + i;
    int c = n0 + tx * 4;
    __half2 r01, r23;
    r01 = __floats2half2_rn(acc[i][0] + bin[c + 0], acc[i][1] + bin[c + 1]);
    r23 = __floats2half2_rn(acc[i][2] + bin[c + 2], acc[i][3] + bin[c + 3]);
    *reinterpret_cast<__half2*>(&QKh[(size_t)row * 1024 + c + 0]) = r01;
    *reinterpret_cast<__half2*>(&QKh[(size_t)row * 1024 + c + 2]) = r23;
  }
}

// ------------- k_attn (MFMA): block = (graph, 16-row tile) ------------------
// S = QK^T/8 via mfma_f32_16x16x32_f16; softmax in LDS; attn-mean in regs;
// per-head column sums atomically into cpbuf.
__global__ __launch_bounds__(256) void k_attn(
    const __half* __restrict__ QKh,
    float* __restrict__ cpbuf,          // [B][8][200], pre-zeroed
    float* __restrict__ attn) {         // [B][200][200]
  const int b  = blockIdx.x / 13;
  const int it = blockIdx.x % 13;
  const int i0 = it * 16;
  const int rows = (SS - i0 >= 16) ? 16 : (SS - i0);   // 16 or 8
  const int t    = threadIdx.x;
  const int wave = t >> 6;
  const int lane = t & 63;
  const int col  = lane & 15;     // MFMA n / m index
  const int quad = lane >> 4;     // MFMA k-group / row-group

  __shared__ __align__(16) _Float16 kS[208][72];   // [col j][d], padded
  __shared__ __align__(16) _Float16 qS[16][72];    // [row i][d]
  __shared__ __align__(16) float    Ss[16][212];   // scores / probs

  // attn-mean register accumulators: thread owns idx = t + 256k (k<13)
  float am[13];
  int   soff[13];    // offset into Ss flat: idx + 12*i  (stride 212 vs 200)
  int   kmax = 0;
#pragma unroll
  for (int k = 0; k < 13; ++k) {
    int idx = t + (k << 8);
    am[k] = 0.f;
    if (idx < rows * 200) {
      int i = idx / 200;
      soff[k] = idx + 12 * i;
      kmax = k + 1;
    } else soff[k] = 0;
  }

  const size_t gbase = (size_t)b * SS * 1024;

  for (int h = 0; h < NHD; ++h) {
    __syncthreads();
    // ---- stage kS[208][64] (rows >=200 zero) and qS[16][64]
#pragma unroll
    for (int p = 0; p < 7; ++p) {
      int li = t + (p << 8);
      if (li < 1664) {
        int j = li >> 3, c = li & 7;
        float4 v = {0.f, 0.f, 0.f, 0.f};
        if (j < SS) v = *reinterpret_cast<const float4*>(
            &QKh[gbase + (size_t)j * 1024 + 512 + h * 64 + c * 8]);
        *reinterpret_cast<float4*>(&kS[j][c * 8]) = v;
      }
    }
    if (t < 128) {
      int i = t >> 3, c = t & 7;
      int gi = i0 + i;
      float4 v = {0.f, 0.f, 0.f, 0.f};
      if (gi < SS) v = *reinterpret_cast<const float4*>(
          &QKh[gbase + (size_t)gi * 1024 + h * 64 + c * 8]);
      *reinterpret_cast<float4*>(&qS[i][c * 8]) = v;
    }
    __syncthreads();
    // ---- MFMA: S[16][208] in 13 col-tiles, wave w takes jt = w,w+4,w+8,w+12
    half8 a0 = *reinterpret_cast<const half8*>(&qS[col][quad * 8]);
    half8 a1 = *reinterpret_cast<const half8*>(&qS[col][32 + quad * 8]);
#pragma unroll
    for (int m = 0; m < 4; ++m) {
      int jt = wave + m * 4;
      if (jt < 13) {
        const int j0 = jt * 16;
        half8 b0 = *reinterpret_cast<const half8*>(&kS[j0 + col][quad * 8]);
        half8 b1 = *reinterpret_cast<const half8*>(&kS[j0 + col][32 + quad * 8]);
        floatx4 acc = {0.f, 0.f, 0.f, 0.f};
        acc = __builtin_amdgcn_mfma_f32_16x16x32_f16(a0, b0, acc, 0, 0, 0);
        acc = __builtin_amdgcn_mfma_f32_16x16x32_f16(a1, b1, acc, 0, 0, 0);
#pragma unroll
        for (int r = 0; r < 4; ++r)
          Ss[quad * 4 + r][j0 + col] = acc[r] * 0.125f;
      }
    }
    __syncthreads();
    // ---- softmax per row (wave handles rows wave*4 .. +3)
#pragma unroll
    for (int ri = 0; ri < 4; ++ri) {
      int r = wave * 4 + ri;
      if (r < rows) {
        float* srow = &Ss[r][0];
        float s0 = srow[lane], s1 = srow[lane + 64], s2 = srow[lane + 128];
        float s3 = (lane < 8) ? srow[lane + 192] : -1e30f;
        float mx = fmaxf(fmaxf(s0, s1), fmaxf(s2, s3));
#pragma unroll
        for (int o = 32; o; o >>= 1) mx = fmaxf(mx, __shfl_xor(mx, o));
        float e0 = __expf(s0 - mx), e1 = __expf(s1 - mx), e2 = __expf(s2 - mx);
        float e3 = (lane < 8) ? __expf(s3 - mx) : 0.f;
        float sum = e0 + e1 + e2 + e3;
#pragma unroll
        for (int o = 32; o; o >>= 1) sum += __shfl_xor(sum, o);
        float rl = 1.0f / sum;
        srow[lane] = e0 * rl; srow[lane + 64] = e1 * rl; srow[lane + 128] = e2 * rl;
        if (lane < 8) srow[lane + 192] = e3 * rl;
      }
    }
    __syncthreads();
    // ---- attn-mean (regs) + per-head column sums
    const float* sflat = &Ss[0][0];
#pragma unroll
    for (int k = 0; k < 13; ++k)
      if (k < kmax) am[k] += sflat[soff[k]] * 0.125f;
    if (t < SS) {
      float s = 0.f;
      for (int i = 0; i < rows; ++i) s += Ss[i][t];
      atomicAdd(&cpbuf[((size_t)b * NHD + h) * SS + t], s);
    }
  }
  // ---- coalesced attn write: addr = (b*200+i0)*200 + idx, idx = t + 256k
  float* abase = &attn[((size_t)b * SS + i0) * SS];
#pragma unroll
  for (int k = 0; k < 13; ++k)
    if (k < kmax) abase[t + (k << 8)] = am[k];
}

// ------------- k_pool: tvec_h = cp_h^T @ xc ; pooled = Wv tvec + bv*200 -----
__global__ __launch_bounds__(256) void k_pool(
    const float* __restrict__ xc, const float* __restrict__ cpbuf,
    const float* __restrict__ Win, const float* __restrict__ bin,
    float* __restrict__ pooled) {
  const int b = blockIdx.x, t = threadIdx.x;
  __shared__ float cps[NHD][SS];
  __shared__ float tvs[NHD][EMB_];
  for (int idx = t; idx < NHD * SS; idx += 256) {
    int h = idx / SS, j = idx - h * SS;
    cps[h][j] = cpbuf[((size_t)b * NHD + h) * SS + j];
  }
  __syncthreads();
  const float* xcb = xc + (size_t)b * SS * EMB_;
  float a0[NHD] = {0.f}, a1[NHD] = {0.f};
  for (int j = 0; j < SS; ++j) {
    float x0 = xcb[(size_t)j * EMB_ + t];
    float x1 = xcb[(size_t)j * EMB_ + t + 256];
#pragma unroll
    for (int h = 0; h < NHD; ++h) {
      float c = cps[h][j];
      a0[h] += c * x0; a1[h] += c * x1;
    }
  }
#pragma unroll
  for (int h = 0; h < NHD; ++h) { tvs[h][t] = a0[h]; tvs[h][t + 256] = a1[h]; }
  __syncthreads();
  const int wv = t >> 6, lane = t & 63;
  for (int e = wv; e < EMB_; e += 4) {
    int h = e >> 6;
    const float* wr = Win + (size_t)(2 * EMB_ + e) * EMB_;
    float s = 0.f;
#pragma unroll
    for (int q = 0; q < 8; ++q) s += wr[lane + q * 64] * tvs[h][lane + q * 64];
#pragma unroll
    for (int o = 32; o; o >>= 1) s += __shfl_xor(s, o);
    if (lane == 0) pooled[(size_t)b * EMB_ + e] = bin[2 * EMB_ + e] * (float)SS + s;
  }
}

// ---------------- readout ----------------
__global__ __launch_bounds__(256) void k_final(
    const float* __restrict__ pooled, const float* __restrict__ Wout,
    const float* __restrict__ bout, const float* __restrict__ finw,
    const float* __restrict__ finb, float* __restrict__ out) {
  const int b = blockIdx.x, t = threadIdx.x;
  __shared__ float pl[EMB_], po[EMB_];
  for (int k = t; k < EMB_; k += 256) pl[k] = pooled[(size_t)b * EMB_ + k] * (1.0f / (float)SS);
  __syncthreads();
  for (int e = t; e < EMB_; e += 256) {
    const float* wr = &Wout[(size_t)e * EMB_];
    float a = bout[e];
    for (int k = 0; k < EMB_; ++k) a += wr[k] * pl[k];
    po[e] = a;
  }
  __syncthreads();
  if (t < HD) {
    float a = finb[t];
    for (int e = 0; e < EMB_; ++e) a += po[e] * finw[(size_t)e * HD + t];
    out[(size_t)b * HD + t] = tanhf(a);
  }
}

// ---------------------------------------------------------------------------
extern "C" void kernel_launch(void* const* d_in, const int* in_sizes, int n_in,
                              void* d_out, int out_size, void* d_ws, size_t ws_size,
                              hipStream_t stream) {
  const float* x         = (const float*)d_in[0];
  const int*   ei        = (const int*)d_in[1];
  const float* gcn_w0    = (const float*)d_in[4];
  const float* gcn_w     = (const float*)d_in[5];
  const float* gcn_b     = (const float*)d_in[6];
  const float* lin1_w0   = (const float*)d_in[7];
  const float* lin1_w    = (const float*)d_in[8];
  const float* lin1_b    = (const float*)d_in[9];
  const float* lin2_w    = (const float*)d_in[10];
  const float* lin2_b    = (const float*)d_in[11];
  const float* sag_w1    = (const float*)d_in[12];
  const float* sag_w2    = (const float*)d_in[13];
  const float* sag_b     = (const float*)d_in[14];
  const float* mha_in_w  = (const float*)d_in[15];
  const float* mha_in_b  = (const float*)d_in[16];
  const float* mha_out_w = (const float*)d_in[17];
  const float* mha_out_b = (const float*)d_in[18];
  const float* fin_w     = (const float*)d_in[19];
  const float* fin_b     = (const float*)d_in[20];

  float* ws     = (float*)d_ws;
  float* dinv   = ws;                                  // 51,200
  float* Araw   = dinv + NT;                           // 10,240,000
  float* buf0   = Araw + (size_t)GB * SS * SS;         // 6,553,600
  float* buf1   = buf0 + (size_t)NT * HD;              // 6,553,600
  float* zbuf   = buf1 + (size_t)NT * HD;              // 6,553,600
  float* xcbuf  = zbuf + (size_t)NT * HD;              // 26,214,400 (xc)
  float* pooled = xcbuf + (size_t)NT * EMB_;           // 131,072
  // QK (fp16) overlays [Araw .. zbuf) once the GCN layers are done:
  __half* QKh  = (__half*)Araw;                        // 52,428,800 halves
  float* cpbuf = Araw + 26214400;                      // 409,600 floats (tail of overlay)

  float* outp = (float*)d_out;                         // [B,128]
  float* attn = outp + (size_t)GB * HD;                // [B,200,200]

  hipMemsetAsync(Araw, 0, (size_t)GB * SS * SS * sizeof(float), stream);

  k_build_A<<<NE_ / 256, 256, 0, stream>>>(ei, ei + NE_, Araw);
  k_dinv<<<NT / 4, 256, 0, stream>>>(Araw, dinv);

  for (int l = 0; l < NLAY; ++l) {
    const float* zin = (l == 0) ? x : zbuf;
    int k1 = (l == 0) ? KIN : HD;
    const float* gw  = (l == 0) ? gcn_w0  : gcn_w  + (size_t)(l - 1) * HD * HD;
    const float* l1w = (l == 0) ? lin1_w0 : lin1_w + (size_t)(l - 1) * 2 * HD * HD;
    k_gemm_node<<<(NT / 64) * 2, 256, 0, stream>>>(zin, k1, nullptr, 0, gw, nullptr, buf0, 0);
    k_gemm_agg<<<GB * 8, 256, 0, stream>>>(Araw, dinv, buf0, gcn_b + l * HD, buf1);
    k_gemm_node<<<(NT / 64) * 2, 256, 0, stream>>>(zin, k1, buf1, HD, l1w, lin1_b + l * HD, buf0, 1);
    k_gemm_node<<<(NT / 64) * 2, 256, 0, stream>>>(buf0, HD, nullptr, 0,
                                                   lin2_w + (size_t)l * HD * HD,
                                                   lin2_b + l * HD, zbuf, 1);
    k_sag<<<GB, 256, 0, stream>>>(zbuf, Araw, sag_w1, sag_w2, sag_b, xcbuf, l);
  }

  // ---- MHA ----
  hipMemsetAsync(cpbuf, 0, (size_t)GB * NHD * SS * sizeof(float), stream);
  k_proj<<<(NT / 64) * 16, 256, 0, stream>>>(xcbuf, mha_in_w, mha_in_b, QKh);
  k_attn<<<GB * 13, 256, 0, stream>>>(QKh, cpbuf, attn);
  k_pool<<<GB, 256, 0, stream>>>(xcbuf, cpbuf, mha_in_w, mha_in_b, pooled);
  k_final<<<GB, 256, 0, stream>>>(pooled, mha_out_w, mha_out_b, fin_w, fin_b, outp);
}

// Round 6
// 3146.746 us; speedup vs baseline: 2.2136x; 1.1515x over previous
//
#include <hip/hip_runtime.h>
#include <hip/hip_fp16.h>

// ---------------------------------------------------------------------------
// GraphConv_8847632629923 : round 5
//   k_proj rewritten on MFMA fp16 (was fp32 VALU, 71 TF, 757 us):
//     128x128 tile, BK=64, 4 waves as 2x2 of 64x64, fp32->fp16 convert at
//     LDS staging, fp32 accumulation. 36.9 KB LDS, 2-way-free bank layout.
//   Everything else identical to round 4 (passing, absmax 1.2e-4).
// ---------------------------------------------------------------------------

#define GB   256          // batch (graphs)
#define SS   200          // nodes per graph
#define KIN  200          // input features
#define HD   128          // hidden
#define NLAY 4
#define NHD  8
#define TOPK 100
#define NT   (GB * SS)    // 51200 nodes
#define EPG_ 6400
#define NE_  (GB * EPG_)  // 1,638,400 edges
#define EMB_ 512

typedef _Float16 half8 __attribute__((ext_vector_type(8)));
typedef _Float16 half4v __attribute__((ext_vector_type(4)));
typedef float floatx4 __attribute__((ext_vector_type(4)));

// ---------------- adjacency build ----------------
__global__ __launch_bounds__(256) void k_build_A(const int* __restrict__ src,
                                                 const int* __restrict__ dst,
                                                 float* __restrict__ A) {
  int e = blockIdx.x * 256 + threadIdx.x;
  if (e >= NE_) return;
  int d = dst[e], s = src[e];
  int b = d / SS;
  int dl = d - b * SS;
  int sl = s - b * SS;
  atomicAdd(&A[((size_t)b * SS + dl) * SS + sl], 1.0f);
}

// ---------------- dinv = rsqrt(in_deg + 1) ----------------
__global__ __launch_bounds__(256) void k_dinv(const float* __restrict__ A,
                                              float* __restrict__ dinv) {
  int node = blockIdx.x * 4 + (threadIdx.x >> 6);
  int lane = threadIdx.x & 63;
  const float* r = A + (size_t)node * SS;
  float v = r[lane] + r[lane + 64] + r[lane + 128];
  if (lane < 8) v += r[lane + 192];
#pragma unroll
  for (int o = 32; o; o >>= 1) v += __shfl_xor(v, o);
  if (lane == 0) dinv[node] = rsqrtf(v + 1.0f);
}

// ---------------- node GEMM: out[N,128] = act([in1|in2] @ W + bias) --------
__global__ __launch_bounds__(256) void k_gemm_node(
    const float* __restrict__ in1, int k1,
    const float* __restrict__ in2, int k2,        // optional, stride 128
    const float* __restrict__ W,                  // [k1+k2][128]
    const float* __restrict__ bias,               // [128] or null
    float* __restrict__ out, int doTanh) {
  const int row0 = (blockIdx.x >> 1) * 64;
  const int n0   = (blockIdx.x & 1) * 64;
  const int t  = threadIdx.x;
  const int tx = t & 15, ty = t >> 4;
  const int K = k1 + k2;
  __shared__ __align__(16) float As[32][68];
  __shared__ __align__(16) float Bs[32][68];
  float acc[4][4] = {{0.f, 0.f, 0.f, 0.f}, {0.f, 0.f, 0.f, 0.f},
                     {0.f, 0.f, 0.f, 0.f}, {0.f, 0.f, 0.f, 0.f}};
  for (int k0 = 0; k0 < K; k0 += 32) {
    __syncthreads();
#pragma unroll
    for (int p = 0; p < 8; ++p) {
      int li = t + p * 256;
      int kk = li & 31, m = li >> 5;
      int kg = k0 + kk;
      int row = row0 + m;
      float v = 0.f;
      if (kg < k1)     v = in1[(size_t)row * k1 + kg];
      else if (kg < K) v = in2[(size_t)row * HD + (kg - k1)];
      As[kk][m] = v;
      int n = li & 63, kb = li >> 6;
      int kg2 = k0 + kb;
      Bs[kb][n] = (kg2 < K) ? W[(size_t)kg2 * HD + n0 + n] : 0.f;
    }
    __syncthreads();
#pragma unroll
    for (int kk = 0; kk < 32; ++kk) {
      float4 av = *reinterpret_cast<const float4*>(&As[kk][ty * 4]);
      float4 wv = *reinterpret_cast<const float4*>(&Bs[kk][tx * 4]);
      float a[4] = {av.x, av.y, av.z, av.w};
      float w[4] = {wv.x, wv.y, wv.z, wv.w};
#pragma unroll
      for (int i = 0; i < 4; ++i)
#pragma unroll
        for (int j = 0; j < 4; ++j) acc[i][j] += a[i] * w[j];
    }
  }
#pragma unroll
  for (int i = 0; i < 4; ++i) {
    int row = row0 + ty * 4 + i;
    int c = n0 + tx * 4;
    float4 r;
    r.x = acc[i][0] + (bias ? bias[c + 0] : 0.f);
    r.y = acc[i][1] + (bias ? bias[c + 1] : 0.f);
    r.z = acc[i][2] + (bias ? bias[c + 2] : 0.f);
    r.w = acc[i][3] + (bias ? bias[c + 3] : 0.f);
    if (doTanh) { r.x = tanhf(r.x); r.y = tanhf(r.y); r.z = tanhf(r.z); r.w = tanhf(r.w); }
    *reinterpret_cast<float4*>(&out[(size_t)row * HD + c]) = r;
  }
}

// --------- GCN aggregation: x1 = tanh( Â @ xw + b ), Â normalized on load ---
__global__ __launch_bounds__(256) void k_gemm_agg(
    const float* __restrict__ A, const float* __restrict__ dinv,
    const float* __restrict__ xw, const float* __restrict__ bias,
    float* __restrict__ out) {
  const int b    = blockIdx.x >> 3;
  const int row0 = ((blockIdx.x >> 1) & 3) * 64;
  const int n0   = (blockIdx.x & 1) * 64;
  const int t  = threadIdx.x;
  const int tx = t & 15, ty = t >> 4;
  const float* Ab = A + (size_t)b * SS * SS;
  const float* dv = dinv + b * SS;
  __shared__ __align__(16) float As[32][68];
  __shared__ __align__(16) float Bs[32][68];
  float acc[4][4] = {{0.f, 0.f, 0.f, 0.f}, {0.f, 0.f, 0.f, 0.f},
                     {0.f, 0.f, 0.f, 0.f}, {0.f, 0.f, 0.f, 0.f}};
  for (int k0 = 0; k0 < SS; k0 += 32) {
    __syncthreads();
#pragma unroll
    for (int p = 0; p < 8; ++p) {
      int li = t + p * 256;
      int kk = li & 31, m = li >> 5;
      int d = row0 + m;
      int sg = k0 + kk;
      float v = 0.f;
      if (d < SS && sg < SS) {
        v = Ab[(size_t)d * SS + sg];
        if (d == sg) v += 1.0f;               // self-loop
        v *= dv[d] * dv[sg];                  // D^-1/2 (A+I) D^-1/2
      }
      As[kk][m] = v;
      int n = li & 63, kb = li >> 6;
      int sg2 = k0 + kb;
      Bs[kb][n] = (sg2 < SS) ? xw[((size_t)b * SS + sg2) * HD + n0 + n] : 0.f;
    }
    __syncthreads();
#pragma unroll
    for (int kk = 0; kk < 32; ++kk) {
      float4 av = *reinterpret_cast<const float4*>(&As[kk][ty * 4]);
      float4 wv = *reinterpret_cast<const float4*>(&Bs[kk][tx * 4]);
      float a[4] = {av.x, av.y, av.z, av.w};
      float w[4] = {wv.x, wv.y, wv.z, wv.w};
#pragma unroll
      for (int i = 0; i < 4; ++i)
#pragma unroll
        for (int j = 0; j < 4; ++j) acc[i][j] += a[i] * w[j];
    }
  }
#pragma unroll
  for (int i = 0; i < 4; ++i) {
    int row = row0 + ty * 4 + i;
    if (row >= SS) continue;
    int c = n0 + tx * 4;
    float4 r;
    r.x = tanhf(acc[i][0] + bias[c + 0]);
    r.y = tanhf(acc[i][1] + bias[c + 1]);
    r.z = tanhf(acc[i][2] + bias[c + 2]);
    r.w = tanhf(acc[i][3] + bias[c + 3]);
    *reinterpret_cast<float4*>(&out[((size_t)b * SS + row) * HD + c]) = r;
  }
}

// ---------------- SAGPool: score, top-k select, padded write ----------------
__global__ __launch_bounds__(256) void k_sag(
    const float* __restrict__ z, const float* __restrict__ A,
    const float* __restrict__ w1, const float* __restrict__ w2,
    const float* __restrict__ sb, float* __restrict__ xc, int layer) {
  const int b = blockIdx.x, t = threadIdx.x;
  __shared__ float w1s[HD], w2s[HD];
  __shared__ float zw1[SS], sc[SS], fac[SS];
  if (t < HD) { w1s[t] = w1[t]; w2s[t] = w2[t]; }
  __syncthreads();
  float a2 = 0.f;
  if (t < SS) {
    const float4* zr = reinterpret_cast<const float4*>(&z[((size_t)b * SS + t) * HD]);
    float a1 = 0.f;
#pragma unroll
    for (int q = 0; q < HD / 4; ++q) {
      float4 v = zr[q];
      a1 += v.x * w1s[4 * q] + v.y * w1s[4 * q + 1] + v.z * w1s[4 * q + 2] + v.w * w1s[4 * q + 3];
      a2 += v.x * w2s[4 * q] + v.y * w2s[4 * q + 1] + v.z * w2s[4 * q + 2] + v.w * w2s[4 * q + 3];
    }
    zw1[t] = a1;
  }
  __syncthreads();
  if (t < SS) {
    float s = sb[0] + a2;
    const float4* ar = reinterpret_cast<const float4*>(&A[((size_t)b * SS + t) * SS]);
#pragma unroll 5
    for (int q = 0; q < SS / 4; ++q) {
      float4 v = ar[q];
      s += v.x * zw1[4 * q] + v.y * zw1[4 * q + 1] + v.z * zw1[4 * q + 2] + v.w * zw1[4 * q + 3];
    }
    sc[t] = s;
  }
  __syncthreads();
  if (t < SS) {
    float si = sc[t];
    int cnt = 0;
    for (int j = 0; j < SS; ++j) {
      float sj = sc[j];
      cnt += (sj > si || (sj == si && j < t)) ? 1 : 0;
    }
    fac[t] = (cnt < TOPK) ? tanhf(si) : 0.f;
  }
  __syncthreads();
  for (int idx = t; idx < SS * HD; idx += 256) {
    int row = idx >> 7, c = idx & 127;
    xc[((size_t)b * SS + row) * EMB_ + layer * HD + c] =
        fac[row] * z[((size_t)b * SS + row) * HD + c];
  }
}

// ------------- k_proj (MFMA fp16): QK[N,1024] = xc @ [Wq|Wk]^T + b ----------
// block = (M-tile 128 rows, N-tile 128 cols); 8 consecutive blocks share the
// A-tile (bm = bx>>3) for L2 reuse. BK=64, fp32->fp16 convert at staging.
__global__ __launch_bounds__(256) void k_proj(
    const float* __restrict__ xc, const float* __restrict__ Win,
    const float* __restrict__ bin, __half* __restrict__ QKh) {
  const int bm = blockIdx.x >> 3;        // 0..399
  const int bn = blockIdx.x & 7;         // 0..7
  const int m0 = bm * 128, n0 = bn * 128;
  const int t    = threadIdx.x;
  const int wave = t >> 6, lane = t & 63;
  const int col  = lane & 15, quad = lane >> 4;
  const int wm = (wave & 1) * 64;        // wave row offset in tile
  const int wn = (wave >> 1) * 64;       // wave col offset in tile
  __shared__ __align__(16) _Float16 As[128][72];   // [m][k], 2-way-free banks
  __shared__ __align__(16) _Float16 Bs[128][72];   // [n][k]
  floatx4 acc[4][4] = {};
  const int lr = t >> 1;                 // staging row 0..127
  const int lk = (t & 1) * 32;           // staging k offset 0/32

  for (int k0 = 0; k0 < EMB_; k0 += 64) {
    __syncthreads();
    const float4* ga = reinterpret_cast<const float4*>(&xc [(size_t)(m0 + lr) * EMB_ + k0 + lk]);
    const float4* gb = reinterpret_cast<const float4*>(&Win[(size_t)(n0 + lr) * EMB_ + k0 + lk]);
#pragma unroll
    for (int q = 0; q < 8; ++q) {
      float4 va = ga[q];
      half4v ha = {(_Float16)va.x, (_Float16)va.y, (_Float16)va.z, (_Float16)va.w};
      *reinterpret_cast<half4v*>(&As[lr][lk + q * 4]) = ha;
      float4 vb = gb[q];
      half4v hb = {(_Float16)vb.x, (_Float16)vb.y, (_Float16)vb.z, (_Float16)vb.w};
      *reinterpret_cast<half4v*>(&Bs[lr][lk + q * 4]) = hb;
    }
    __syncthreads();
#pragma unroll
    for (int ks = 0; ks < 2; ++ks) {
      half8 af[4], bf[4];
#pragma unroll
      for (int i = 0; i < 4; ++i)
        af[i] = *reinterpret_cast<const half8*>(&As[wm + i * 16 + col][ks * 32 + quad * 8]);
#pragma unroll
      for (int j = 0; j < 4; ++j)
        bf[j] = *reinterpret_cast<const half8*>(&Bs[wn + j * 16 + col][ks * 32 + quad * 8]);
#pragma unroll
      for (int i = 0; i < 4; ++i)
#pragma unroll
        for (int j = 0; j < 4; ++j)
          acc[i][j] = __builtin_amdgcn_mfma_f32_16x16x32_f16(af[i], bf[j], acc[i][j], 0, 0, 0);
    }
  }
  // epilogue: C/D layout col=lane&15, row=quad*4+reg
#pragma unroll
  for (int j = 0; j < 4; ++j) {
    int c = n0 + wn + j * 16 + col;
    float bb = bin[c];
#pragma unroll
    for (int i = 0; i < 4; ++i) {
      int rbase = m0 + wm + i * 16 + quad * 4;
#pragma unroll
      for (int r = 0; r < 4; ++r)
        QKh[(size_t)(rbase + r) * 1024 + c] = __float2half(acc[i][j][r] + bb);
    }
  }
}

// ------------- k_attn (MFMA): block = (graph, 16-row tile) ------------------
__global__ __launch_bounds__(256) void k_attn(
    const __half* __restrict__ QKh,
    float* __restrict__ cpbuf,          // [B][8][200], pre-zeroed
    float* __restrict__ attn) {         // [B][200][200]
  const int b  = blockIdx.x / 13;
  const int it = blockIdx.x % 13;
  const int i0 = it * 16;
  const int rows = (SS - i0 >= 16) ? 16 : (SS - i0);   // 16 or 8
  const int t    = threadIdx.x;
  const int wave = t >> 6;
  const int lane = t & 63;
  const int col  = lane & 15;
  const int quad = lane >> 4;

  __shared__ __align__(16) _Float16 kS[208][72];
  __shared__ __align__(16) _Float16 qS[16][72];
  __shared__ __align__(16) float    Ss[16][212];

  float am[13];
  int   soff[13];
  int   kmax = 0;
#pragma unroll
  for (int k = 0; k < 13; ++k) {
    int idx = t + (k << 8);
    am[k] = 0.f;
    if (idx < rows * 200) {
      int i = idx / 200;
      soff[k] = idx + 12 * i;
      kmax = k + 1;
    } else soff[k] = 0;
  }

  const size_t gbase = (size_t)b * SS * 1024;

  for (int h = 0; h < NHD; ++h) {
    __syncthreads();
#pragma unroll
    for (int p = 0; p < 7; ++p) {
      int li = t + (p << 8);
      if (li < 1664) {
        int j = li >> 3, c = li & 7;
        float4 v = {0.f, 0.f, 0.f, 0.f};
        if (j < SS) v = *reinterpret_cast<const float4*>(
            &QKh[gbase + (size_t)j * 1024 + 512 + h * 64 + c * 8]);
        *reinterpret_cast<float4*>(&kS[j][c * 8]) = v;
      }
    }
    if (t < 128) {
      int i = t >> 3, c = t & 7;
      int gi = i0 + i;
      float4 v = {0.f, 0.f, 0.f, 0.f};
      if (gi < SS) v = *reinterpret_cast<const float4*>(
          &QKh[gbase + (size_t)gi * 1024 + h * 64 + c * 8]);
      *reinterpret_cast<float4*>(&qS[i][c * 8]) = v;
    }
    __syncthreads();
    half8 a0 = *reinterpret_cast<const half8*>(&qS[col][quad * 8]);
    half8 a1 = *reinterpret_cast<const half8*>(&qS[col][32 + quad * 8]);
#pragma unroll
    for (int m = 0; m < 4; ++m) {
      int jt = wave + m * 4;
      if (jt < 13) {
        const int j0 = jt * 16;
        half8 b0 = *reinterpret_cast<const half8*>(&kS[j0 + col][quad * 8]);
        half8 b1 = *reinterpret_cast<const half8*>(&kS[j0 + col][32 + quad * 8]);
        floatx4 acc = {0.f, 0.f, 0.f, 0.f};
        acc = __builtin_amdgcn_mfma_f32_16x16x32_f16(a0, b0, acc, 0, 0, 0);
        acc = __builtin_amdgcn_mfma_f32_16x16x32_f16(a1, b1, acc, 0, 0, 0);
#pragma unroll
        for (int r = 0; r < 4; ++r)
          Ss[quad * 4 + r][j0 + col] = acc[r] * 0.125f;
      }
    }
    __syncthreads();
#pragma unroll
    for (int ri = 0; ri < 4; ++ri) {
      int r = wave * 4 + ri;
      if (r < rows) {
        float* srow = &Ss[r][0];
        float s0 = srow[lane], s1 = srow[lane + 64], s2 = srow[lane + 128];
        float s3 = (lane < 8) ? srow[lane + 192] : -1e30f;
        float mx = fmaxf(fmaxf(s0, s1), fmaxf(s2, s3));
#pragma unroll
        for (int o = 32; o; o >>= 1) mx = fmaxf(mx, __shfl_xor(mx, o));
        float e0 = __expf(s0 - mx), e1 = __expf(s1 - mx), e2 = __expf(s2 - mx);
        float e3 = (lane < 8) ? __expf(s3 - mx) : 0.f;
        float sum = e0 + e1 + e2 + e3;
#pragma unroll
        for (int o = 32; o; o >>= 1) sum += __shfl_xor(sum, o);
        float rl = 1.0f / sum;
        srow[lane] = e0 * rl; srow[lane + 64] = e1 * rl; srow[lane + 128] = e2 * rl;
        if (lane < 8) srow[lane + 192] = e3 * rl;
      }
    }
    __syncthreads();
    const float* sflat = &Ss[0][0];
#pragma unroll
    for (int k = 0; k < 13; ++k)
      if (k < kmax) am[k] += sflat[soff[k]] * 0.125f;
    if (t < SS) {
      float s = 0.f;
      for (int i = 0; i < rows; ++i) s += Ss[i][t];
      atomicAdd(&cpbuf[((size_t)b * NHD + h) * SS + t], s);
    }
  }
  float* abase = &attn[((size_t)b * SS + i0) * SS];
#pragma unroll
  for (int k = 0; k < 13; ++k)
    if (k < kmax) abase[t + (k << 8)] = am[k];
}

// ------------- k_pool: tvec_h = cp_h^T @ xc ; pooled = Wv tvec + bv*200 -----
__global__ __launch_bounds__(256) void k_pool(
    const float* __restrict__ xc, const float* __restrict__ cpbuf,
    const float* __restrict__ Win, const float* __restrict__ bin,
    float* __restrict__ pooled) {
  const int b = blockIdx.x, t = threadIdx.x;
  __shared__ float cps[NHD][SS];
  __shared__ float tvs[NHD][EMB_];
  for (int idx = t; idx < NHD * SS; idx += 256) {
    int h = idx / SS, j = idx - h * SS;
    cps[h][j] = cpbuf[((size_t)b * NHD + h) * SS + j];
  }
  __syncthreads();
  const float* xcb = xc + (size_t)b * SS * EMB_;
  float a0[NHD] = {0.f}, a1[NHD] = {0.f};
  for (int j = 0; j < SS; ++j) {
    float x0 = xcb[(size_t)j * EMB_ + t];
    float x1 = xcb[(size_t)j * EMB_ + t + 256];
#pragma unroll
    for (int h = 0; h < NHD; ++h) {
      float c = cps[h][j];
      a0[h] += c * x0; a1[h] += c * x1;
    }
  }
#pragma unroll
  for (int h = 0; h < NHD; ++h) { tvs[h][t] = a0[h]; tvs[h][t + 256] = a1[h]; }
  __syncthreads();
  const int wv = t >> 6, lane = t & 63;
  for (int e = wv; e < EMB_; e += 4) {
    int h = e >> 6;
    const float* wr = Win + (size_t)(2 * EMB_ + e) * EMB_;
    float s = 0.f;
#pragma unroll
    for (int q = 0; q < 8; ++q) s += wr[lane + q * 64] * tvs[h][lane + q * 64];
#pragma unroll
    for (int o = 32; o; o >>= 1) s += __shfl_xor(s, o);
    if (lane == 0) pooled[(size_t)b * EMB_ + e] = bin[2 * EMB_ + e] * (float)SS + s;
  }
}

// ---------------- readout ----------------
__global__ __launch_bounds__(256) void k_final(
    const float* __restrict__ pooled, const float* __restrict__ Wout,
    const float* __restrict__ bout, const float* __restrict__ finw,
    const float* __restrict__ finb, float* __restrict__ out) {
  const int b = blockIdx.x, t = threadIdx.x;
  __shared__ float pl[EMB_], po[EMB_];
  for (int k = t; k < EMB_; k += 256) pl[k] = pooled[(size_t)b * EMB_ + k] * (1.0f / (float)SS);
  __syncthreads();
  for (int e = t; e < EMB_; e += 256) {
    const float* wr = &Wout[(size_t)e * EMB_];
    float a = bout[e];
    for (int k = 0; k < EMB_; ++k) a += wr[k] * pl[k];
    po[e] = a;
  }
  __syncthreads();
  if (t < HD) {
    float a = finb[t];
    for (int e = 0; e < EMB_; ++e) a += po[e] * finw[(size_t)e * HD + t];
    out[(size_t)b * HD + t] = tanhf(a);
  }
}

// ---------------------------------------------------------------------------
extern "C" void kernel_launch(void* const* d_in, const int* in_sizes, int n_in,
                              void* d_out, int out_size, void* d_ws, size_t ws_size,
                              hipStream_t stream) {
  const float* x         = (const float*)d_in[0];
  const int*   ei        = (const int*)d_in[1];
  const float* gcn_w0    = (const float*)d_in[4];
  const float* gcn_w     = (const float*)d_in[5];
  const float* gcn_b     = (const float*)d_in[6];
  const float* lin1_w0   = (const float*)d_in[7];
  const float* lin1_w    = (const float*)d_in[8];
  const float* lin1_b    = (const float*)d_in[9];
  const float* lin2_w    = (const float*)d_in[10];
  const float* lin2_b    = (const float*)d_in[11];
  const float* sag_w1    = (const float*)d_in[12];
  const float* sag_w2    = (const float*)d_in[13];
  const float* sag_b     = (const float*)d_in[14];
  const float* mha_in_w  = (const float*)d_in[15];
  const float* mha_in_b  = (const float*)d_in[16];
  const float* mha_out_w = (const float*)d_in[17];
  const float* mha_out_b = (const float*)d_in[18];
  const float* fin_w     = (const float*)d_in[19];
  const float* fin_b     = (const float*)d_in[20];

  float* ws     = (float*)d_ws;
  float* dinv   = ws;                                  // 51,200
  float* Araw   = dinv + NT;                           // 10,240,000
  float* buf0   = Araw + (size_t)GB * SS * SS;         // 6,553,600
  float* buf1   = buf0 + (size_t)NT * HD;              // 6,553,600
  float* zbuf   = buf1 + (size_t)NT * HD;              // 6,553,600
  float* xcbuf  = zbuf + (size_t)NT * HD;              // 26,214,400 (xc)
  float* pooled = xcbuf + (size_t)NT * EMB_;           // 131,072
  // QK (fp16) overlays [Araw .. zbuf-tail) once the GCN layers are done:
  __half* QKh  = (__half*)Araw;                        // 52,428,800 halves
  float* cpbuf = Araw + 26214400;                      // 409,600 floats (tail of overlay)

  float* outp = (float*)d_out;                         // [B,128]
  float* attn = outp + (size_t)GB * HD;                // [B,200,200]

  hipMemsetAsync(Araw, 0, (size_t)GB * SS * SS * sizeof(float), stream);

  k_build_A<<<NE_ / 256, 256, 0, stream>>>(ei, ei + NE_, Araw);
  k_dinv<<<NT / 4, 256, 0, stream>>>(Araw, dinv);

  for (int l = 0; l < NLAY; ++l) {
    const float* zin = (l == 0) ? x : zbuf;
    int k1 = (l == 0) ? KIN : HD;
    const float* gw  = (l == 0) ? gcn_w0  : gcn_w  + (size_t)(l - 1) * HD * HD;
    const float* l1w = (l == 0) ? lin1_w0 : lin1_w + (size_t)(l - 1) * 2 * HD * HD;
    k_gemm_node<<<(NT / 64) * 2, 256, 0, stream>>>(zin, k1, nullptr, 0, gw, nullptr, buf0, 0);
    k_gemm_agg<<<GB * 8, 256, 0, stream>>>(Araw, dinv, buf0, gcn_b + l * HD, buf1);
    k_gemm_node<<<(NT / 64) * 2, 256, 0, stream>>>(zin, k1, buf1, HD, l1w, lin1_b + l * HD, buf0, 1);
    k_gemm_node<<<(NT / 64) * 2, 256, 0, stream>>>(buf0, HD, nullptr, 0,
                                                   lin2_w + (size_t)l * HD * HD,
                                                   lin2_b + l * HD, zbuf, 1);
    k_sag<<<GB, 256, 0, stream>>>(zbuf, Araw, sag_w1, sag_w2, sag_b, xcbuf, l);
  }

  // ---- MHA ----
  hipMemsetAsync(cpbuf, 0, (size_t)GB * NHD * SS * sizeof(float), stream);
  k_proj<<<(NT / 128) * 8, 256, 0, stream>>>(xcbuf, mha_in_w, mha_in_b, QKh);
  k_attn<<<GB * 13, 256, 0, stream>>>(QKh, cpbuf, attn);
  k_pool<<<GB, 256, 0, stream>>>(xcbuf, cpbuf, mha_in_w, mha_in_b, pooled);
  k_final<<<GB, 256, 0, stream>>>(pooled, mha_out_w, mha_out_b, fin_w, fin_b, outp);
}